// Round 1
// baseline (299.700 us; speedup 1.0000x reference)
//
#include <hip/hip_runtime.h>
#include <hip/hip_bf16.h>
#include <math.h>

#define DIMX 1024
#define HEADSX 16
#define HDX 64
#define BBX 2
#define SSX 2048
#define MMX (BBX*SSX)   // 4096 rows

typedef __bf16 bf16x8 __attribute__((ext_vector_type(8)));
typedef __bf16 bf16x4 __attribute__((ext_vector_type(4)));
typedef float  f32x4  __attribute__((ext_vector_type(4)));

#define NEGF (-1e30f)

// async 16B global->LDS. LDS dest must be wave-uniform base; HW adds lane*16.
static __device__ __forceinline__ void gload16(const void* g, void* l) {
  __builtin_amdgcn_global_load_lds(
      (const __attribute__((address_space(1))) unsigned int*)g,
      (__attribute__((address_space(3))) unsigned int*)l, 16, 0, 0);
}

// ---------------- kernel 1: x fp32 -> bf16 (same layout) ----------------
__global__ __launch_bounds__(256) void k_convert_x(const float* __restrict__ x,
                                                   __bf16* __restrict__ xb) {
  int i = (blockIdx.x * 256 + threadIdx.x) * 4;
  float4 v = *(const float4*)&x[i];
  bf16x4 o = { (__bf16)v.x, (__bf16)v.y, (__bf16)v.z, (__bf16)v.w };
  *(bf16x4*)&xb[i] = o;
}

// ------------- kernel 2: W [K][N] fp32 -> W^T [N][K] bf16 ---------------
__global__ __launch_bounds__(256) void k_transpose_w(
    const float* __restrict__ Wq, const float* __restrict__ Wk,
    const float* __restrict__ Wv, const float* __restrict__ Wo,
    __bf16* __restrict__ wqkvT, __bf16* __restrict__ woT) {
  __shared__ __bf16 tile[64][65];
  const int mat = blockIdx.y;
  const float* src = (mat == 0) ? Wq : (mat == 1) ? Wk : (mat == 2) ? Wv : Wo;
  __bf16* dst = (mat < 3) ? (wqkvT + (size_t)mat * DIMX * DIMX) : woT;
  const int tx = blockIdx.x & 15, ty = blockIdx.x >> 4;
  const int k0 = ty * 64, n0 = tx * 64;
  #pragma unroll
  for (int rep = 0; rep < 16; ++rep) {
    int idx = rep * 256 + threadIdx.x;
    int r = idx >> 6, c = idx & 63;
    tile[r][c] = (__bf16)src[(size_t)(k0 + r) * DIMX + n0 + c];
  }
  __syncthreads();
  #pragma unroll
  for (int rep = 0; rep < 16; ++rep) {
    int idx = rep * 256 + threadIdx.x;
    int r = idx >> 6, c = idx & 63;           // r = local n, c = local k
    dst[(size_t)(n0 + r) * DIMX + k0 + c] = tile[c][r];
  }
}

// ---------------- kernels 3/5: bf16 GEMM, 128x128 tile, BK=32 ----------------
// C[m][n] = sum_k A[m][k]*Bt[n][k] (+bias). EPI=0: QKV scatter, EPI=1: fp32 out.
template<int EPI>
__global__ __launch_bounds__(256) void k_gemm(
    const __bf16* __restrict__ A,    // [M][1024]
    const __bf16* __restrict__ Bt,   // [N][1024]
    const float* __restrict__ b0, const float* __restrict__ b1,
    const float* __restrict__ b2,
    __bf16* __restrict__ qb, __bf16* __restrict__ kb, __bf16* __restrict__ vtb,
    float* __restrict__ outf) {
  constexpr int BK = 32, K = 1024;
  __shared__ __bf16 As[128 * BK];
  __shared__ __bf16 Bs[128 * BK];
  const int tid = threadIdx.x, lane = tid & 63, wave = tid >> 6;
  const int g = lane >> 4, r16 = lane & 15;
  const int wm = wave & 1, wn = wave >> 1;
  const int m0 = blockIdx.x * 128, n0 = blockIdx.y * 128;

  f32x4 acc[4][4] = {};

  for (int k0 = 0; k0 < K; k0 += BK) {
    __syncthreads();   // previous iteration's ds_reads done before overwrite
    #pragma unroll
    for (int i = 0; i < 2; ++i) {
      int c = wave * 64 + lane + 256 * i;       // chunk id (512 x 16B per tile)
      gload16(&A [(size_t)(m0 + (c >> 2)) * K + k0 + (c & 3) * 8],
              (char*)As + (size_t)(wave * 64 + 256 * i) * 16);
      gload16(&Bt[(size_t)(n0 + (c >> 2)) * K + k0 + (c & 3) * 8],
              (char*)Bs + (size_t)(wave * 64 + 256 * i) * 16);
    }
    __syncthreads();   // compiler drains vmcnt(0) before barrier
    bf16x8 af[4], bfr[4];
    #pragma unroll
    for (int i = 0; i < 4; ++i)
      af[i]  = *(const bf16x8*)&As[(wm * 64 + i * 16 + r16) * BK + g * 8];
    #pragma unroll
    for (int j = 0; j < 4; ++j)
      bfr[j] = *(const bf16x8*)&Bs[(wn * 64 + j * 16 + r16) * BK + g * 8];
    #pragma unroll
    for (int i = 0; i < 4; ++i)
      #pragma unroll
      for (int j = 0; j < 4; ++j)
        acc[i][j] = __builtin_amdgcn_mfma_f32_16x16x32_bf16(af[i], bfr[j],
                                                            acc[i][j], 0, 0, 0);
  }

  #pragma unroll
  for (int i = 0; i < 4; ++i) {
    #pragma unroll
    for (int j = 0; j < 4; ++j) {
      #pragma unroll
      for (int r = 0; r < 4; ++r) {
        int m = m0 + wm * 64 + i * 16 + 4 * g + r;   // C row = (lane>>4)*4+reg
        int n = n0 + wn * 64 + j * 16 + r16;         // C col = lane&15
        float v = acc[i][j][r];
        if constexpr (EPI == 0) {
          int proj = n >> 10, w = n & 1023, h = w >> 6, d = w & 63;
          const float* bp = (proj == 0) ? b0 : (proj == 1) ? b1 : b2;
          v += bp[w];
          int b = m >> 11, s = m & 2047, bh = b * HEADSX + h;
          if (proj == 0)      qb [((size_t)bh * SSX + s) * HDX + d] = (__bf16)v;
          else if (proj == 1) kb [((size_t)bh * SSX + s) * HDX + d] = (__bf16)v;
          else                vtb[((size_t)bh * HDX + d) * SSX + s] = (__bf16)v;
        } else {
          outf[(size_t)m * DIMX + n] = v + b0[n];
        }
      }
    }
  }
}

// ---------------- kernel 4: causal flash attention ----------------
// One wave owns 16 q rows. KVBLK=32. Q,K: [B,H,S,hd] bf16; V: [B,H,hd,S] bf16.
__global__ __launch_bounds__(256) void k_attn(
    const __bf16* __restrict__ qb, const __bf16* __restrict__ kb,
    const __bf16* __restrict__ vtb, __bf16* __restrict__ ctxb) {
  const int lane = threadIdx.x & 63, wq = threadIdx.x >> 6;
  const int g = lane >> 4, r16 = lane & 15;
  const int bh = blockIdx.y;
  const int q0 = blockIdx.x * 64 + wq * 16;
  const int b = bh >> 4, h = bh & 15;

  const __bf16* Q  = qb  + (size_t)bh * SSX * HDX;
  const __bf16* Kp = kb  + (size_t)bh * SSX * HDX;
  const __bf16* Vt = vtb + (size_t)bh * HDX * SSX;

  __shared__ __bf16 Pl[4][16 * 32];   // per-wave P tile

  bf16x8 qf[2];
  qf[0] = *(const bf16x8*)&Q[(size_t)(q0 + r16) * HDX + g * 8];
  qf[1] = *(const bf16x8*)&Q[(size_t)(q0 + r16) * HDX + 32 + g * 8];

  f32x4 acc[4] = {};
  float mrun[4], lrun[4];
  #pragma unroll
  for (int r = 0; r < 4; ++r) { mrun[r] = NEGF; lrun[r] = 0.f; }

  const int ntiles = (q0 + 15) / 32 + 1;   // causal: only tiles touching diag
  const float scale = 0.125f;              // 1/sqrt(64)

  for (int t = 0; t < ntiles; ++t) {
    const int kv0 = t * 32;
    // ---- S = Q K^T (16 x 32) ----
    f32x4 sac[2] = {};
    #pragma unroll
    for (int jj = 0; jj < 2; ++jj)
      #pragma unroll
      for (int kk = 0; kk < 2; ++kk) {
        bf16x8 kf = *(const bf16x8*)&Kp[(size_t)(kv0 + jj * 16 + r16) * HDX +
                                        kk * 32 + g * 8];
        sac[jj] = __builtin_amdgcn_mfma_f32_16x16x32_bf16(qf[kk], kf, sac[jj],
                                                          0, 0, 0);
      }
    // ---- mask + online softmax ----
    float sv[2][4], tmax[4];
    #pragma unroll
    for (int r = 0; r < 4; ++r) tmax[r] = NEGF;
    #pragma unroll
    for (int jj = 0; jj < 2; ++jj)
      #pragma unroll
      for (int r = 0; r < 4; ++r) {
        float s = sac[jj][r] * scale;
        int kcol = kv0 + jj * 16 + r16;
        int qrow = q0 + 4 * g + r;
        s = (kcol > qrow) ? NEGF : s;
        sv[jj][r] = s;
        tmax[r] = fmaxf(tmax[r], s);
      }
    #pragma unroll
    for (int r = 0; r < 4; ++r)
      #pragma unroll
      for (int off = 1; off < 16; off <<= 1)
        tmax[r] = fmaxf(tmax[r], __shfl_xor(tmax[r], off));
    float fac[4], rsum[4];
    #pragma unroll
    for (int r = 0; r < 4; ++r) {
      float mnew = fmaxf(mrun[r], tmax[r]);
      fac[r] = __expf(mrun[r] - mnew);   // first tile: exp(-huge) = 0
      mrun[r] = mnew;
      rsum[r] = 0.f;
    }
    #pragma unroll
    for (int jj = 0; jj < 2; ++jj)
      #pragma unroll
      for (int r = 0; r < 4; ++r) {
        float p = __expf(sv[jj][r] - mrun[r]);  // masked: exp(-huge)=0
        rsum[r] += p;
        Pl[wq][(4 * g + r) * 32 + jj * 16 + r16] = (__bf16)p;
      }
    #pragma unroll
    for (int r = 0; r < 4; ++r) {
      #pragma unroll
      for (int off = 1; off < 16; off <<= 1)
        rsum[r] += __shfl_xor(rsum[r], off);
      lrun[r] = lrun[r] * fac[r] + rsum[r];
    }
    #pragma unroll
    for (int j2 = 0; j2 < 4; ++j2)
      #pragma unroll
      for (int r = 0; r < 4; ++r)
        acc[j2][r] *= fac[r];
    // same-wave LDS write->read: drain lgkm to be safe
    asm volatile("s_waitcnt lgkmcnt(0)" ::: "memory");
    // ---- ctx += P V ----
    bf16x8 pf = *(const bf16x8*)&Pl[wq][r16 * 32 + g * 8];
    #pragma unroll
    for (int j2 = 0; j2 < 4; ++j2) {
      bf16x8 vf = *(const bf16x8*)&Vt[(size_t)(j2 * 16 + r16) * SSX +
                                      kv0 + g * 8];
      acc[j2] = __builtin_amdgcn_mfma_f32_16x16x32_bf16(pf, vf, acc[j2],
                                                        0, 0, 0);
    }
  }
  float inv[4];
  #pragma unroll
  for (int r = 0; r < 4; ++r) inv[r] = 1.f / lrun[r];
  #pragma unroll
  for (int j2 = 0; j2 < 4; ++j2)
    #pragma unroll
    for (int r = 0; r < 4; ++r) {
      int s = q0 + 4 * g + r;
      int d = j2 * 16 + r16;
      ctxb[((size_t)(b * SSX + s)) * DIMX + h * HDX + d] =
          (__bf16)(acc[j2][r] * inv[r]);
    }
}

extern "C" void kernel_launch(void* const* d_in, const int* in_sizes, int n_in,
                              void* d_out, int out_size, void* d_ws,
                              size_t ws_size, hipStream_t stream) {
  const float* x  = (const float*)d_in[0];
  const float* Wq = (const float*)d_in[1];
  const float* bq = (const float*)d_in[2];
  const float* Wk = (const float*)d_in[3];
  const float* bk = (const float*)d_in[4];
  const float* Wv = (const float*)d_in[5];
  const float* bv = (const float*)d_in[6];
  const float* Wo = (const float*)d_in[7];
  const float* bo = (const float*)d_in[8];
  float* out = (float*)d_out;

  char* ws = (char*)d_ws;                       // needs 40 MB
  __bf16* xb    = (__bf16*)(ws);                // 8 MB, reused as ctxb later
  __bf16* wqkvT = (__bf16*)(ws + ((size_t)8  << 20));  // 6 MB
  __bf16* woT   = (__bf16*)(ws + ((size_t)14 << 20));  // 2 MB
  __bf16* qb    = (__bf16*)(ws + ((size_t)16 << 20));  // 8 MB
  __bf16* kb    = (__bf16*)(ws + ((size_t)24 << 20));  // 8 MB
  __bf16* vtb   = (__bf16*)(ws + ((size_t)32 << 20));  // 8 MB (V^T)
  __bf16* ctxb  = xb;   // x dead after QKV GEMM

  k_convert_x<<<4096, 256, 0, stream>>>(x, xb);
  k_transpose_w<<<dim3(256, 4), 256, 0, stream>>>(Wq, Wk, Wv, Wo, wqkvT, woT);
  k_gemm<0><<<dim3(32, 24), 256, 0, stream>>>(xb, wqkvT, bq, bk, bv,
                                              qb, kb, vtb, nullptr);
  k_attn<<<dim3(32, 32), 256, 0, stream>>>(qb, kb, vtb, ctxb);
  k_gemm<1><<<dim3(32, 8), 256, 0, stream>>>(ctxb, woT, bo, nullptr, nullptr,
                                             nullptr, nullptr, nullptr, out);
}

// Round 2
// 298.672 us; speedup vs baseline: 1.0034x; 1.0034x over previous
//
#include <hip/hip_runtime.h>
#include <hip/hip_bf16.h>
#include <math.h>

#define DIMX 1024
#define HEADSX 16
#define HDX 64
#define BBX 2
#define SSX 2048
#define MMX (BBX*SSX)   // 4096 rows

typedef __bf16 bf16x8 __attribute__((ext_vector_type(8)));
typedef __bf16 bf16x4 __attribute__((ext_vector_type(4)));
typedef float  f32x4  __attribute__((ext_vector_type(4)));

#define NEGF (-1e30f)

// async 16B global->LDS. LDS dest must be wave-uniform base; HW adds lane*16.
static __device__ __forceinline__ void gload16(const void* g, void* l) {
  __builtin_amdgcn_global_load_lds(
      (const __attribute__((address_space(1))) unsigned int*)g,
      (__attribute__((address_space(3))) unsigned int*)l, 16, 0, 0);
}

// ---------------- kernel 1: x fp32 -> bf16 (same layout) ----------------
__global__ __launch_bounds__(256) void k_convert_x(const float* __restrict__ x,
                                                   __bf16* __restrict__ xb) {
  int i = (blockIdx.x * 256 + threadIdx.x) * 4;
  float4 v = *(const float4*)&x[i];
  bf16x4 o = { (__bf16)v.x, (__bf16)v.y, (__bf16)v.z, (__bf16)v.w };
  *(bf16x4*)&xb[i] = o;
}

// ------------- kernel 2: W [K][N] fp32 -> W^T [N][K] bf16 ---------------
__global__ __launch_bounds__(256) void k_transpose_w(
    const float* __restrict__ Wq, const float* __restrict__ Wk,
    const float* __restrict__ Wv, const float* __restrict__ Wo,
    __bf16* __restrict__ wqkvT, __bf16* __restrict__ woT) {
  __shared__ __bf16 tile[64][65];
  const int mat = blockIdx.y;
  const float* src = (mat == 0) ? Wq : (mat == 1) ? Wk : (mat == 2) ? Wv : Wo;
  __bf16* dst = (mat < 3) ? (wqkvT + (size_t)mat * DIMX * DIMX) : woT;
  const int tx = blockIdx.x & 15, ty = blockIdx.x >> 4;
  const int k0 = ty * 64, n0 = tx * 64;
  #pragma unroll
  for (int rep = 0; rep < 16; ++rep) {
    int idx = rep * 256 + threadIdx.x;
    int r = idx >> 6, c = idx & 63;
    tile[r][c] = (__bf16)src[(size_t)(k0 + r) * DIMX + n0 + c];
  }
  __syncthreads();
  #pragma unroll
  for (int rep = 0; rep < 16; ++rep) {
    int idx = rep * 256 + threadIdx.x;
    int r = idx >> 6, c = idx & 63;           // r = local n, c = local k
    dst[(size_t)(n0 + r) * DIMX + k0 + c] = tile[c][r];
  }
}

// ---------------- kernels 3/5: bf16 GEMM, 128x128 tile, BK=32 ----------------
// C[m][n] = sum_k A[m][k]*Bt[n][k] (+bias). EPI=0: QKV scatter, EPI=1: fp32 out.
template<int EPI>
__global__ __launch_bounds__(256) void k_gemm(
    const __bf16* __restrict__ A,    // [M][1024]
    const __bf16* __restrict__ Bt,   // [N][1024]
    const float* __restrict__ b0, const float* __restrict__ b1,
    const float* __restrict__ b2,
    __bf16* __restrict__ qb, __bf16* __restrict__ kb, __bf16* __restrict__ vtb,
    float* __restrict__ outf) {
  constexpr int BK = 32, K = 1024;
  __shared__ __bf16 As[128 * BK];
  __shared__ __bf16 Bs[128 * BK];
  const int tid = threadIdx.x, lane = tid & 63, wave = tid >> 6;
  const int g = lane >> 4, r16 = lane & 15;
  const int wm = wave & 1, wn = wave >> 1;
  const int m0 = blockIdx.x * 128, n0 = blockIdx.y * 128;

  f32x4 acc[4][4] = {};

  for (int k0 = 0; k0 < K; k0 += BK) {
    __syncthreads();   // previous iteration's ds_reads done before overwrite
    #pragma unroll
    for (int i = 0; i < 2; ++i) {
      int c = wave * 64 + lane + 256 * i;       // chunk id (512 x 16B per tile)
      gload16(&A [(size_t)(m0 + (c >> 2)) * K + k0 + (c & 3) * 8],
              (char*)As + (size_t)(wave * 64 + 256 * i) * 16);
      gload16(&Bt[(size_t)(n0 + (c >> 2)) * K + k0 + (c & 3) * 8],
              (char*)Bs + (size_t)(wave * 64 + 256 * i) * 16);
    }
    __syncthreads();   // compiler drains vmcnt(0) before barrier
    bf16x8 af[4], bfr[4];
    #pragma unroll
    for (int i = 0; i < 4; ++i)
      af[i]  = *(const bf16x8*)&As[(wm * 64 + i * 16 + r16) * BK + g * 8];
    #pragma unroll
    for (int j = 0; j < 4; ++j)
      bfr[j] = *(const bf16x8*)&Bs[(wn * 64 + j * 16 + r16) * BK + g * 8];
    #pragma unroll
    for (int i = 0; i < 4; ++i)
      #pragma unroll
      for (int j = 0; j < 4; ++j)
        acc[i][j] = __builtin_amdgcn_mfma_f32_16x16x32_bf16(af[i], bfr[j],
                                                            acc[i][j], 0, 0, 0);
  }

  #pragma unroll
  for (int i = 0; i < 4; ++i) {
    #pragma unroll
    for (int j = 0; j < 4; ++j) {
      #pragma unroll
      for (int r = 0; r < 4; ++r) {
        int m = m0 + wm * 64 + i * 16 + 4 * g + r;   // C row = (lane>>4)*4+reg
        int n = n0 + wn * 64 + j * 16 + r16;         // C col = lane&15
        float v = acc[i][j][r];
        if constexpr (EPI == 0) {
          int proj = n >> 10, w = n & 1023, h = w >> 6, d = w & 63;
          const float* bp = (proj == 0) ? b0 : (proj == 1) ? b1 : b2;
          v += bp[w];
          int b = m >> 11, s = m & 2047, bh = b * HEADSX + h;
          if (proj == 0)      qb [((size_t)bh * SSX + s) * HDX + d] = (__bf16)v;
          else if (proj == 1) kb [((size_t)bh * SSX + s) * HDX + d] = (__bf16)v;
          else                vtb[((size_t)bh * HDX + d) * SSX + s] = (__bf16)v;
        } else {
          outf[(size_t)m * DIMX + n] = v + b0[n];
        }
      }
    }
  }
}

// ---------------- kernel 4: causal flash attention, KVBLK=64 ----------------
// One wave owns 16 q rows. Q,K: [B,H,S,hd] bf16; V: [B,H,hd,S] bf16.
// P goes through per-wave LDS with XOR-swizzled 8-elem column blocks
// (row-stride 128B would otherwise be a 16-way bank conflict on ds_read_b128).
__global__ __launch_bounds__(256) void k_attn(
    const __bf16* __restrict__ qb, const __bf16* __restrict__ kb,
    const __bf16* __restrict__ vtb, __bf16* __restrict__ ctxb) {
  const int lane = threadIdx.x & 63, wq = threadIdx.x >> 6;
  const int g = lane >> 4, r16 = lane & 15;
  const int bh = blockIdx.y;
  const int qx = gridDim.x - 1 - blockIdx.x;   // LPT: heaviest q-blocks first
  const int q0 = qx * 64 + wq * 16;
  const int b = bh >> 4, h = bh & 15;

  const __bf16* Q  = qb  + (size_t)bh * SSX * HDX;
  const __bf16* Kp = kb  + (size_t)bh * SSX * HDX;
  const __bf16* Vt = vtb + (size_t)bh * HDX * SSX;

  __shared__ __bf16 Pl[4][16 * 64];   // 2 KB per wave

  bf16x8 qf[2];
  qf[0] = *(const bf16x8*)&Q[(size_t)(q0 + r16) * HDX + g * 8];
  qf[1] = *(const bf16x8*)&Q[(size_t)(q0 + r16) * HDX + 32 + g * 8];

  f32x4 acc[4] = {};
  float mrun[4], lrun[4];
  #pragma unroll
  for (int r = 0; r < 4; ++r) { mrun[r] = NEGF; lrun[r] = 0.f; }

  const int ntiles = q0 / 64 + 1;   // KVBLK=64, covers kv <= q0+15
  const float scale = 0.125f;      // 1/sqrt(64)

  for (int t = 0; t < ntiles; ++t) {
    const int kv0 = t * 64;
    // ---- S = Q K^T (16 x 64) ----
    f32x4 sac[4] = {};
    #pragma unroll
    for (int kk = 0; kk < 2; ++kk)
      #pragma unroll
      for (int jj = 0; jj < 4; ++jj) {
        bf16x8 kf = *(const bf16x8*)&Kp[(size_t)(kv0 + jj * 16 + r16) * HDX +
                                        kk * 32 + g * 8];
        sac[jj] = __builtin_amdgcn_mfma_f32_16x16x32_bf16(qf[kk], kf, sac[jj],
                                                          0, 0, 0);
      }
    // ---- mask + online softmax ----
    float sv[4][4], tmax[4];
    #pragma unroll
    for (int r = 0; r < 4; ++r) tmax[r] = NEGF;
    #pragma unroll
    for (int jj = 0; jj < 4; ++jj)
      #pragma unroll
      for (int r = 0; r < 4; ++r) {
        float s = sac[jj][r] * scale;
        int kcol = kv0 + jj * 16 + r16;
        int qrow = q0 + 4 * g + r;
        s = (kcol > qrow) ? NEGF : s;
        sv[jj][r] = s;
        tmax[r] = fmaxf(tmax[r], s);
      }
    #pragma unroll
    for (int r = 0; r < 4; ++r)
      #pragma unroll
      for (int off = 1; off < 16; off <<= 1)
        tmax[r] = fmaxf(tmax[r], __shfl_xor(tmax[r], off));
    float fac[4], rsum[4];
    #pragma unroll
    for (int r = 0; r < 4; ++r) {
      float mnew = fmaxf(mrun[r], tmax[r]);
      fac[r] = __expf(mrun[r] - mnew);   // first tile: exp(-huge) = 0
      mrun[r] = mnew;
      rsum[r] = 0.f;
    }
    #pragma unroll
    for (int jj = 0; jj < 4; ++jj)
      #pragma unroll
      for (int r = 0; r < 4; ++r) {
        float p = __expf(sv[jj][r] - mrun[r]);  // masked: exp(-huge)=0
        rsum[r] += p;
        int row = 4 * g + r;
        int cb = (jj * 2 + (r16 >> 3)) ^ (row & 7);   // swizzled 8-col block
        Pl[wq][row * 64 + cb * 8 + (r16 & 7)] = (__bf16)p;
      }
    #pragma unroll
    for (int r = 0; r < 4; ++r) {
      #pragma unroll
      for (int off = 1; off < 16; off <<= 1)
        rsum[r] += __shfl_xor(rsum[r], off);
      lrun[r] = lrun[r] * fac[r] + rsum[r];
    }
    #pragma unroll
    for (int j2 = 0; j2 < 4; ++j2)
      #pragma unroll
      for (int r = 0; r < 4; ++r)
        acc[j2][r] *= fac[r];
    // ---- ctx += P V ----  (compiler inserts the lgkmcnt wait for Pl)
    bf16x8 pf[2];
    #pragma unroll
    for (int half = 0; half < 2; ++half) {
      int xb = (half * 4 + g) ^ (r16 & 7);
      pf[half] = *(const bf16x8*)&Pl[wq][r16 * 64 + xb * 8];
    }
    #pragma unroll
    for (int j2 = 0; j2 < 4; ++j2)
      #pragma unroll
      for (int half = 0; half < 2; ++half) {
        bf16x8 vf = *(const bf16x8*)&Vt[(size_t)(j2 * 16 + r16) * SSX +
                                        kv0 + half * 32 + g * 8];
        acc[j2] = __builtin_amdgcn_mfma_f32_16x16x32_bf16(pf[half], vf,
                                                          acc[j2], 0, 0, 0);
      }
  }
  float inv[4];
  #pragma unroll
  for (int r = 0; r < 4; ++r) inv[r] = 1.f / lrun[r];
  #pragma unroll
  for (int j2 = 0; j2 < 4; ++j2)
    #pragma unroll
    for (int r = 0; r < 4; ++r) {
      int s = q0 + 4 * g + r;
      int d = j2 * 16 + r16;
      ctxb[((size_t)(b * SSX + s)) * DIMX + h * HDX + d] =
          (__bf16)(acc[j2][r] * inv[r]);
    }
}

extern "C" void kernel_launch(void* const* d_in, const int* in_sizes, int n_in,
                              void* d_out, int out_size, void* d_ws,
                              size_t ws_size, hipStream_t stream) {
  const float* x  = (const float*)d_in[0];
  const float* Wq = (const float*)d_in[1];
  const float* bq = (const float*)d_in[2];
  const float* Wk = (const float*)d_in[3];
  const float* bk = (const float*)d_in[4];
  const float* Wv = (const float*)d_in[5];
  const float* bv = (const float*)d_in[6];
  const float* Wo = (const float*)d_in[7];
  const float* bo = (const float*)d_in[8];
  float* out = (float*)d_out;

  char* ws = (char*)d_ws;                       // needs 40 MB
  __bf16* xb    = (__bf16*)(ws);                // 8 MB, reused as ctxb later
  __bf16* wqkvT = (__bf16*)(ws + ((size_t)8  << 20));  // 6 MB
  __bf16* woT   = (__bf16*)(ws + ((size_t)14 << 20));  // 2 MB
  __bf16* qb    = (__bf16*)(ws + ((size_t)16 << 20));  // 8 MB
  __bf16* kb    = (__bf16*)(ws + ((size_t)24 << 20));  // 8 MB
  __bf16* vtb   = (__bf16*)(ws + ((size_t)32 << 20));  // 8 MB (V^T)
  __bf16* ctxb  = xb;   // x dead after QKV GEMM

  k_convert_x<<<4096, 256, 0, stream>>>(x, xb);
  k_transpose_w<<<dim3(256, 4), 256, 0, stream>>>(Wq, Wk, Wv, Wo, wqkvT, woT);
  k_gemm<0><<<dim3(32, 24), 256, 0, stream>>>(xb, wqkvT, bq, bk, bv,
                                              qb, kb, vtb, nullptr);
  k_attn<<<dim3(32, 32), 256, 0, stream>>>(qb, kb, vtb, ctxb);
  k_gemm<1><<<dim3(32, 8), 256, 0, stream>>>(ctxb, woT, bo, nullptr, nullptr,
                                             nullptr, nullptr, nullptr, out);
}

// Round 3
// 167.248 us; speedup vs baseline: 1.7919x; 1.7858x over previous
//
#include <hip/hip_runtime.h>
#include <hip/hip_bf16.h>
#include <math.h>

#define DIMX 1024
#define HEADSX 16
#define HDX 64
#define BBX 2
#define SSX 2048
#define MMX (BBX*SSX)   // 4096 rows

typedef __bf16 bf16x8 __attribute__((ext_vector_type(8)));
typedef __bf16 bf16x4 __attribute__((ext_vector_type(4)));
typedef float  f32x4  __attribute__((ext_vector_type(4)));

#define NEGF (-1e30f)

// async 16B global->LDS. LDS dest must be wave-uniform base; HW adds lane*16.
static __device__ __forceinline__ void gload16(const void* g, void* l) {
  __builtin_amdgcn_global_load_lds(
      (const __attribute__((address_space(1))) unsigned int*)g,
      (__attribute__((address_space(3))) unsigned int*)l, 16, 0, 0);
}

// ---------------- kernel 1: x fp32 -> bf16 (same layout) ----------------
__global__ __launch_bounds__(256) void k_convert_x(const float* __restrict__ x,
                                                   __bf16* __restrict__ xb) {
  int i = (blockIdx.x * 256 + threadIdx.x) * 4;
  float4 v = *(const float4*)&x[i];
  bf16x4 o = { (__bf16)v.x, (__bf16)v.y, (__bf16)v.z, (__bf16)v.w };
  *(bf16x4*)&xb[i] = o;
}

// ------------- kernel 2: W [K][N] fp32 -> W^T [N][K] bf16 ---------------
__global__ __launch_bounds__(256) void k_transpose_w(
    const float* __restrict__ Wq, const float* __restrict__ Wk,
    const float* __restrict__ Wv, const float* __restrict__ Wo,
    __bf16* __restrict__ wqkvT, __bf16* __restrict__ woT) {
  __shared__ __bf16 tile[64][65];
  const int mat = blockIdx.y;
  const float* src = (mat == 0) ? Wq : (mat == 1) ? Wk : (mat == 2) ? Wv : Wo;
  __bf16* dst = (mat < 3) ? (wqkvT + (size_t)mat * DIMX * DIMX) : woT;
  const int tx = blockIdx.x & 15, ty = blockIdx.x >> 4;
  const int k0 = ty * 64, n0 = tx * 64;
  #pragma unroll
  for (int rep = 0; rep < 16; ++rep) {
    int idx = rep * 256 + threadIdx.x;
    int r = idx >> 6, c = idx & 63;
    tile[r][c] = (__bf16)src[(size_t)(k0 + r) * DIMX + n0 + c];
  }
  __syncthreads();
  #pragma unroll
  for (int rep = 0; rep < 16; ++rep) {
    int idx = rep * 256 + threadIdx.x;
    int r = idx >> 6, c = idx & 63;           // r = local n, c = local k
    dst[(size_t)(n0 + r) * DIMX + k0 + c] = tile[c][r];
  }
}

// ---------------- kernels 3/5: bf16 GEMM, 128x128 tile, BK=32 ----------------
// C[m][n] = sum_k A[m][k]*Bt[n][k] (+bias). EPI=0: QKV scatter, EPI=1: fp32 out.
template<int EPI>
__global__ __launch_bounds__(256) void k_gemm(
    const __bf16* __restrict__ A,    // [M][1024]
    const __bf16* __restrict__ Bt,   // [N][1024]
    const float* __restrict__ b0, const float* __restrict__ b1,
    const float* __restrict__ b2,
    __bf16* __restrict__ qb, __bf16* __restrict__ kb, __bf16* __restrict__ vtb,
    float* __restrict__ outf) {
  constexpr int BK = 32, K = 1024;
  __shared__ __bf16 As[128 * BK];
  __shared__ __bf16 Bs[128 * BK];
  const int tid = threadIdx.x, lane = tid & 63, wave = tid >> 6;
  const int g = lane >> 4, r16 = lane & 15;
  const int wm = wave & 1, wn = wave >> 1;
  const int m0 = blockIdx.x * 128, n0 = blockIdx.y * 128;

  f32x4 acc[4][4] = {};

  for (int k0 = 0; k0 < K; k0 += BK) {
    __syncthreads();   // previous iteration's ds_reads done before overwrite
    #pragma unroll
    for (int i = 0; i < 2; ++i) {
      int c = wave * 64 + lane + 256 * i;       // chunk id (512 x 16B per tile)
      gload16(&A [(size_t)(m0 + (c >> 2)) * K + k0 + (c & 3) * 8],
              (char*)As + (size_t)(wave * 64 + 256 * i) * 16);
      gload16(&Bt[(size_t)(n0 + (c >> 2)) * K + k0 + (c & 3) * 8],
              (char*)Bs + (size_t)(wave * 64 + 256 * i) * 16);
    }
    __syncthreads();   // compiler drains vmcnt(0) before barrier
    bf16x8 af[4], bfr[4];
    #pragma unroll
    for (int i = 0; i < 4; ++i)
      af[i]  = *(const bf16x8*)&As[(wm * 64 + i * 16 + r16) * BK + g * 8];
    #pragma unroll
    for (int j = 0; j < 4; ++j)
      bfr[j] = *(const bf16x8*)&Bs[(wn * 64 + j * 16 + r16) * BK + g * 8];
    #pragma unroll
    for (int i = 0; i < 4; ++i)
      #pragma unroll
      for (int j = 0; j < 4; ++j)
        acc[i][j] = __builtin_amdgcn_mfma_f32_16x16x32_bf16(af[i], bfr[j],
                                                            acc[i][j], 0, 0, 0);
  }

  #pragma unroll
  for (int i = 0; i < 4; ++i) {
    #pragma unroll
    for (int j = 0; j < 4; ++j) {
      #pragma unroll
      for (int r = 0; r < 4; ++r) {
        int m = m0 + wm * 64 + i * 16 + 4 * g + r;   // C row = (lane>>4)*4+reg
        int n = n0 + wn * 64 + j * 16 + r16;         // C col = lane&15
        float v = acc[i][j][r];
        if constexpr (EPI == 0) {
          int proj = n >> 10, w = n & 1023, h = w >> 6, d = w & 63;
          const float* bp = (proj == 0) ? b0 : (proj == 1) ? b1 : b2;
          v += bp[w];
          int b = m >> 11, s = m & 2047, bh = b * HEADSX + h;
          if (proj == 0)      qb [((size_t)bh * SSX + s) * HDX + d] = (__bf16)v;
          else if (proj == 1) kb [((size_t)bh * SSX + s) * HDX + d] = (__bf16)v;
          else                vtb[((size_t)bh * HDX + d) * SSX + s] = (__bf16)v;
        } else {
          outf[(size_t)m * DIMX + n] = v + b0[n];
        }
      }
    }
  }
}

// ---------------- kernel 4: causal flash attention ----------------
// 4 waves/block, 16 q-rows each; block covers 64 q rows. All 4 waves share the
// SAME kv-tiles 0..qx -> K/V staged in block LDS, double-buffered via
// global_load_lds (linear dest + inverse-swizzled SOURCE, XOR-swizzled read:
// rule 21). One __syncthreads per tile = the 2-phase template (stage t+1
// issued BEFORE compute t; barrier's vmcnt(0) drain lands after compute).
__global__ __launch_bounds__(256, 4) void k_attn(
    const __bf16* __restrict__ qb, const __bf16* __restrict__ kb,
    const __bf16* __restrict__ vtb, __bf16* __restrict__ ctxb) {
  const int tid = threadIdx.x;
  const int lane = tid & 63, wq = tid >> 6;
  const int g = lane >> 4, r16 = lane & 15;
  const int bh = blockIdx.y;
  const int qx = gridDim.x - 1 - blockIdx.x;   // LPT: heaviest q-blocks first
  const int q0 = qx * 64 + wq * 16;
  const int b = bh >> 4, h = bh & 15;

  const __bf16* Q  = qb  + (size_t)bh * SSX * HDX;
  const __bf16* Kp = kb  + (size_t)bh * SSX * HDX;
  const __bf16* Vt = vtb + (size_t)bh * HDX * SSX;

  __shared__ __bf16 Ks[2][64 * 64];   // 2 x 8 KB
  __shared__ __bf16 Vs[2][64 * 64];   // 2 x 8 KB
  __shared__ __bf16 Pl[4][16 * 64];   // 2 KB per wave

  bf16x8 qf[2];
  qf[0] = *(const bf16x8*)&Q[(size_t)(q0 + r16) * HDX + g * 8];
  qf[1] = *(const bf16x8*)&Q[(size_t)(q0 + r16) * HDX + 32 + g * 8];

  f32x4 acc[4] = {};
  float mrun[4], lrun[4];
  #pragma unroll
  for (int r = 0; r < 4; ++r) { mrun[r] = NEGF; lrun[r] = 0.f; }

  const int ntiles = qx + 1;                       // same for all 4 waves
  const float scale2 = 0.18033688011112042f;       // (1/8) * log2(e)

  // stage tile t (64 kv x 64) of K and V into buf. 512 chunks each, 2/thread.
  // LDS chunk (r, cb) receives global chunk (r, cb ^ (r&7))  [read undoes it]
  auto STAGE = [&](int buf, int t) {
    const int kv0 = t * 64;
    #pragma unroll
    for (int i = 0; i < 2; ++i) {
      int c = tid + 256 * i;
      int r = c >> 3;
      int cb = (c & 7) ^ (r & 7);
      gload16(&Kp[(size_t)(kv0 + r) * HDX + cb * 8],
              (char*)Ks[buf] + (size_t)(wq * 64 + 256 * i) * 16);
      gload16(&Vt[(size_t)r * SSX + kv0 + cb * 8],
              (char*)Vs[buf] + (size_t)(wq * 64 + 256 * i) * 16);
    }
  };

  STAGE(0, 0);
  __syncthreads();

  for (int t = 0; t < ntiles; ++t) {
    const int cur = t & 1;
    if (t + 1 < ntiles) STAGE(cur ^ 1, t + 1);   // async prefetch next tile
    const int kv0 = t * 64;

    // ---- S = Q K^T (16 x 64) from LDS ----
    f32x4 sac[4] = {};
    #pragma unroll
    for (int kk = 0; kk < 2; ++kk)
      #pragma unroll
      for (int jj = 0; jj < 4; ++jj) {
        int rr = jj * 16 + r16;
        bf16x8 kf = *(const bf16x8*)
            &Ks[cur][rr * 64 + (((kk << 2) + g) ^ (rr & 7)) * 8];
        sac[jj] = __builtin_amdgcn_mfma_f32_16x16x32_bf16(qf[kk], kf, sac[jj],
                                                          0, 0, 0);
      }

    // ---- scale (+ causal mask, last tile only) ----
    float sv[4][4], tmax[4];
    #pragma unroll
    for (int r = 0; r < 4; ++r) tmax[r] = NEGF;
    const bool last = (t == ntiles - 1);
    #pragma unroll
    for (int jj = 0; jj < 4; ++jj)
      #pragma unroll
      for (int r = 0; r < 4; ++r) {
        float s = sac[jj][r] * scale2;
        if (last) {
          int kcol = kv0 + jj * 16 + r16;
          int qrow = q0 + 4 * g + r;
          s = (kcol > qrow) ? NEGF : s;
        }
        sv[jj][r] = s;
        tmax[r] = fmaxf(tmax[r], s);
      }
    #pragma unroll
    for (int r = 0; r < 4; ++r)
      #pragma unroll
      for (int off = 1; off < 16; off <<= 1)
        tmax[r] = fmaxf(tmax[r], __shfl_xor(tmax[r], off));

    float fac[4];
    #pragma unroll
    for (int r = 0; r < 4; ++r) {
      float mnew = fmaxf(mrun[r], tmax[r]);
      fac[r] = exp2f(mrun[r] - mnew);   // first tile: exp2(-huge) = 0
      mrun[r] = mnew;
    }
    float rsum[4] = {0.f, 0.f, 0.f, 0.f};   // lane-partial; reduced at end
    #pragma unroll
    for (int jj = 0; jj < 4; ++jj)
      #pragma unroll
      for (int r = 0; r < 4; ++r) {
        float p = exp2f(sv[jj][r] - mrun[r]);  // masked: exp2(-huge)=0
        rsum[r] += p;
        int row = 4 * g + r;
        int cb = (jj * 2 + (r16 >> 3)) ^ (row & 7);   // swizzled 8-col block
        Pl[wq][row * 64 + cb * 8 + (r16 & 7)] = (__bf16)p;
      }
    #pragma unroll
    for (int r = 0; r < 4; ++r) lrun[r] = lrun[r] * fac[r] + rsum[r];
    #pragma unroll
    for (int j2 = 0; j2 < 4; ++j2)
      #pragma unroll
      for (int r = 0; r < 4; ++r)
        acc[j2][r] *= fac[r];

    // ---- ctx += P V (V from LDS) ----
    bf16x8 pf[2];
    #pragma unroll
    for (int half = 0; half < 2; ++half) {
      int xb = (half * 4 + g) ^ (r16 & 7);
      pf[half] = *(const bf16x8*)&Pl[wq][r16 * 64 + xb * 8];
    }
    #pragma unroll
    for (int j2 = 0; j2 < 4; ++j2)
      #pragma unroll
      for (int half = 0; half < 2; ++half) {
        int dd = j2 * 16 + r16;
        bf16x8 vf = *(const bf16x8*)
            &Vs[cur][dd * 64 + (((half << 2) + g) ^ (dd & 7)) * 8];
        acc[j2] = __builtin_amdgcn_mfma_f32_16x16x32_bf16(pf[half], vf,
                                                          acc[j2], 0, 0, 0);
      }
    __syncthreads();   // drains prefetch (vmcnt) + all LDS reads (lgkm)
  }

  // deferred row-sum reduction (fac was lane-uniform, so this commutes)
  #pragma unroll
  for (int r = 0; r < 4; ++r)
    #pragma unroll
    for (int off = 1; off < 16; off <<= 1)
      lrun[r] += __shfl_xor(lrun[r], off);

  float inv[4];
  #pragma unroll
  for (int r = 0; r < 4; ++r) inv[r] = 1.f / lrun[r];
  #pragma unroll
  for (int j2 = 0; j2 < 4; ++j2)
    #pragma unroll
    for (int r = 0; r < 4; ++r) {
      int s = q0 + 4 * g + r;
      int d = j2 * 16 + r16;
      ctxb[((size_t)(b * SSX + s)) * DIMX + h * HDX + d] =
          (__bf16)(acc[j2][r] * inv[r]);
    }
}

extern "C" void kernel_launch(void* const* d_in, const int* in_sizes, int n_in,
                              void* d_out, int out_size, void* d_ws,
                              size_t ws_size, hipStream_t stream) {
  const float* x  = (const float*)d_in[0];
  const float* Wq = (const float*)d_in[1];
  const float* bq = (const float*)d_in[2];
  const float* Wk = (const float*)d_in[3];
  const float* bk = (const float*)d_in[4];
  const float* Wv = (const float*)d_in[5];
  const float* bv = (const float*)d_in[6];
  const float* Wo = (const float*)d_in[7];
  const float* bo = (const float*)d_in[8];
  float* out = (float*)d_out;

  char* ws = (char*)d_ws;                       // needs 40 MB
  __bf16* xb    = (__bf16*)(ws);                // 8 MB, reused as ctxb later
  __bf16* wqkvT = (__bf16*)(ws + ((size_t)8  << 20));  // 6 MB
  __bf16* woT   = (__bf16*)(ws + ((size_t)14 << 20));  // 2 MB
  __bf16* qb    = (__bf16*)(ws + ((size_t)16 << 20));  // 8 MB
  __bf16* kb    = (__bf16*)(ws + ((size_t)24 << 20));  // 8 MB
  __bf16* vtb   = (__bf16*)(ws + ((size_t)32 << 20));  // 8 MB (V^T)
  __bf16* ctxb  = xb;   // x dead after QKV GEMM

  k_convert_x<<<4096, 256, 0, stream>>>(x, xb);
  k_transpose_w<<<dim3(256, 4), 256, 0, stream>>>(Wq, Wk, Wv, Wo, wqkvT, woT);
  k_gemm<0><<<dim3(32, 24), 256, 0, stream>>>(xb, wqkvT, bq, bk, bv,
                                              qb, kb, vtb, nullptr);
  k_attn<<<dim3(32, 32), 256, 0, stream>>>(qb, kb, vtb, ctxb);
  k_gemm<1><<<dim3(32, 8), 256, 0, stream>>>(ctxb, woT, bo, nullptr, nullptr,
                                             nullptr, nullptr, nullptr, out);
}

// Round 4
// 133.996 us; speedup vs baseline: 2.2366x; 1.2482x over previous
//
#include <hip/hip_runtime.h>
#include <hip/hip_bf16.h>
#include <math.h>

#define DIMX 1024
#define HEADSX 16
#define HDX 64
#define BBX 2
#define SSX 2048
#define MMX (BBX*SSX)   // 4096 rows

typedef __bf16 bf16x8 __attribute__((ext_vector_type(8)));
typedef __bf16 bf16x4 __attribute__((ext_vector_type(4)));
typedef float  f32x4  __attribute__((ext_vector_type(4)));

#define NEGF (-1e30f)

// async 16B global->LDS. LDS dest must be wave-uniform base; HW adds lane*16.
static __device__ __forceinline__ void gload16(const void* g, void* l) {
  __builtin_amdgcn_global_load_lds(
      (const __attribute__((address_space(1))) unsigned int*)g,
      (__attribute__((address_space(3))) unsigned int*)l, 16, 0, 0);
}

// ---------------- kernel 1: x fp32 -> bf16 (same layout) ----------------
__global__ __launch_bounds__(256) void k_convert_x(const float* __restrict__ x,
                                                   __bf16* __restrict__ xb) {
  int i = (blockIdx.x * 256 + threadIdx.x) * 4;
  float4 v = *(const float4*)&x[i];
  bf16x4 o = { (__bf16)v.x, (__bf16)v.y, (__bf16)v.z, (__bf16)v.w };
  *(bf16x4*)&xb[i] = o;
}

// ------------- kernel 2: W [K][N] fp32 -> W^T [N][K] bf16 ---------------
__global__ __launch_bounds__(256) void k_transpose_w(
    const float* __restrict__ Wq, const float* __restrict__ Wk,
    const float* __restrict__ Wv, const float* __restrict__ Wo,
    __bf16* __restrict__ wqkvT, __bf16* __restrict__ woT) {
  __shared__ __bf16 tile[64][65];
  const int mat = blockIdx.y;
  const float* src = (mat == 0) ? Wq : (mat == 1) ? Wk : (mat == 2) ? Wv : Wo;
  __bf16* dst = (mat < 3) ? (wqkvT + (size_t)mat * DIMX * DIMX) : woT;
  const int tx = blockIdx.x & 15, ty = blockIdx.x >> 4;
  const int k0 = ty * 64, n0 = tx * 64;
  #pragma unroll
  for (int rep = 0; rep < 16; ++rep) {
    int idx = rep * 256 + threadIdx.x;
    int r = idx >> 6, c = idx & 63;
    tile[r][c] = (__bf16)src[(size_t)(k0 + r) * DIMX + n0 + c];
  }
  __syncthreads();
  #pragma unroll
  for (int rep = 0; rep < 16; ++rep) {
    int idx = rep * 256 + threadIdx.x;
    int r = idx >> 6, c = idx & 63;           // r = local n, c = local k
    dst[(size_t)(n0 + r) * DIMX + k0 + c] = tile[c][r];
  }
}

// ---------------- kernels 3/5: bf16 GEMM, 128x128 tile, BK=32 ----------------
// C[m][n] = sum_k A[m][k]*Bt[n][k] (+bias). EPI=0: QKV scatter, EPI=1: fp32 out.
template<int EPI>
__global__ __launch_bounds__(256) void k_gemm(
    const __bf16* __restrict__ A,    // [M][1024]
    const __bf16* __restrict__ Bt,   // [N][1024]
    const float* __restrict__ b0, const float* __restrict__ b1,
    const float* __restrict__ b2,
    __bf16* __restrict__ qb, __bf16* __restrict__ kb, __bf16* __restrict__ vtb,
    float* __restrict__ outf) {
  constexpr int BK = 32, K = 1024;
  __shared__ __bf16 As[128 * BK];
  __shared__ __bf16 Bs[128 * BK];
  const int tid = threadIdx.x, lane = tid & 63, wave = tid >> 6;
  const int g = lane >> 4, r16 = lane & 15;
  const int wm = wave & 1, wn = wave >> 1;
  const int m0 = blockIdx.x * 128, n0 = blockIdx.y * 128;

  f32x4 acc[4][4] = {};

  for (int k0 = 0; k0 < K; k0 += BK) {
    __syncthreads();   // previous iteration's ds_reads done before overwrite
    #pragma unroll
    for (int i = 0; i < 2; ++i) {
      int c = wave * 64 + lane + 256 * i;       // chunk id (512 x 16B per tile)
      gload16(&A [(size_t)(m0 + (c >> 2)) * K + k0 + (c & 3) * 8],
              (char*)As + (size_t)(wave * 64 + 256 * i) * 16);
      gload16(&Bt[(size_t)(n0 + (c >> 2)) * K + k0 + (c & 3) * 8],
              (char*)Bs + (size_t)(wave * 64 + 256 * i) * 16);
    }
    __syncthreads();   // compiler drains vmcnt(0) before barrier
    bf16x8 af[4], bfr[4];
    #pragma unroll
    for (int i = 0; i < 4; ++i)
      af[i]  = *(const bf16x8*)&As[(wm * 64 + i * 16 + r16) * BK + g * 8];
    #pragma unroll
    for (int j = 0; j < 4; ++j)
      bfr[j] = *(const bf16x8*)&Bs[(wn * 64 + j * 16 + r16) * BK + g * 8];
    #pragma unroll
    for (int i = 0; i < 4; ++i)
      #pragma unroll
      for (int j = 0; j < 4; ++j)
        acc[i][j] = __builtin_amdgcn_mfma_f32_16x16x32_bf16(af[i], bfr[j],
                                                            acc[i][j], 0, 0, 0);
  }

  #pragma unroll
  for (int i = 0; i < 4; ++i) {
    #pragma unroll
    for (int j = 0; j < 4; ++j) {
      #pragma unroll
      for (int r = 0; r < 4; ++r) {
        int m = m0 + wm * 64 + i * 16 + 4 * g + r;   // C row = (lane>>4)*4+reg
        int n = n0 + wn * 64 + j * 16 + r16;         // C col = lane&15
        float v = acc[i][j][r];
        if constexpr (EPI == 0) {
          int proj = n >> 10, w = n & 1023, h = w >> 6, d = w & 63;
          const float* bp = (proj == 0) ? b0 : (proj == 1) ? b1 : b2;
          v += bp[w];
          int b = m >> 11, s = m & 2047, bh = b * HEADSX + h;
          if (proj == 0)      qb [((size_t)bh * SSX + s) * HDX + d] = (__bf16)v;
          else if (proj == 1) kb [((size_t)bh * SSX + s) * HDX + d] = (__bf16)v;
          else                vtb[((size_t)bh * HDX + d) * SSX + s] = (__bf16)v;
        } else {
          outf[(size_t)m * DIMX + n] = v + b0[n];
        }
      }
    }
  }
}

// ---------------- kernel 4: causal flash attention, swapped-QK ----------------
// 4 waves/block, 16 q-rows each. K/V double-buffered in LDS via global_load_lds.
// QK^T computed SWAPPED: mfma(K,Q) -> S^T[k][q], q = lane&15 is lane-local =>
// row-max needs only 2 shuffles (stride 16,32); fac/m/l are scalars.
// P^T -> bf16 via v_cvt_pk_bf16_f32, stored transposed in LDS (quad-swizzled),
// read back as PV B-fragments. PV also swapped: mfma(V^T, P) -> ctx^T[d][q].
// Diagonal qx remap (x+bh)&31 fixes the per-CU same-qx aliasing (256%32==0).
__global__ __launch_bounds__(256, 4) void k_attn(
    const __bf16* __restrict__ qb, const __bf16* __restrict__ kb,
    const __bf16* __restrict__ vtb, __bf16* __restrict__ ctxb) {
  const int tid = threadIdx.x;
  const int lane = tid & 63, wq = tid >> 6;
  const int g = lane >> 4, r16 = lane & 15;
  const int bh = blockIdx.y;
  const int qx = (blockIdx.x + bh) & 31;       // balanced diagonal remap
  const int q0 = qx * 64 + wq * 16;
  const int b = bh >> 4, h = bh & 15;

  const __bf16* Q  = qb  + (size_t)bh * SSX * HDX;
  const __bf16* Kp = kb  + (size_t)bh * SSX * HDX;
  const __bf16* Vt = vtb + (size_t)bh * HDX * SSX;

  __shared__ __bf16 Ks[2][64 * 64];    // 2 x 8 KB
  __shared__ __bf16 Vs[2][64 * 64];    // 2 x 8 KB
  __shared__ unsigned Pld[4][512];     // per-wave P^T (16q x 64k bf16), 2 KB

  bf16x8 qf[2];
  qf[0] = *(const bf16x8*)&Q[(size_t)(q0 + r16) * HDX + g * 8];
  qf[1] = *(const bf16x8*)&Q[(size_t)(q0 + r16) * HDX + 32 + g * 8];

  f32x4 acc[4] = {};                 // ctx^T: acc[j2][r] = ctx[d=j2*16+4g+r][q=r16]
  float mrun = NEGF, lrun = 0.f;     // scalars: q is lane-local
  const int qrow = q0 + r16;

  const int ntiles = qx + 1;                       // same for all 4 waves
  const float scale2 = 0.18033688011112042f;       // (1/8) * log2(e)

  // stage tile t (64 kv x 64) of K and V into buf. 512 chunks each, 2/thread.
  // LDS chunk (r, cb) receives global chunk (r, cb ^ (r&7))  [read undoes it]
  auto STAGE = [&](int buf, int t) {
    const int kv0 = t * 64;
    #pragma unroll
    for (int i = 0; i < 2; ++i) {
      int c = tid + 256 * i;
      int r = c >> 3;
      int cb = (c & 7) ^ (r & 7);
      gload16(&Kp[(size_t)(kv0 + r) * HDX + cb * 8],
              (char*)Ks[buf] + (size_t)(wq * 64 + 256 * i) * 16);
      gload16(&Vt[(size_t)r * SSX + kv0 + cb * 8],
              (char*)Vs[buf] + (size_t)(wq * 64 + 256 * i) * 16);
    }
  };

  STAGE(0, 0);
  __syncthreads();

  for (int t = 0; t < ntiles; ++t) {
    const int cur = t & 1;
    if (t + 1 < ntiles) STAGE(cur ^ 1, t + 1);   // async prefetch next tile
    const int kv0 = t * 64;

    // ---- S^T = K Q^T (64k x 16q): sac[jj][r] = S[k=kv0+16jj+4g+r][q=r16] ----
    f32x4 sac[4] = {};
    #pragma unroll
    for (int kk = 0; kk < 2; ++kk)
      #pragma unroll
      for (int jj = 0; jj < 4; ++jj) {
        int rr = jj * 16 + r16;
        bf16x8 kf = *(const bf16x8*)
            &Ks[cur][rr * 64 + (((kk << 2) + g) ^ (rr & 7)) * 8];
        sac[jj] = __builtin_amdgcn_mfma_f32_16x16x32_bf16(kf, qf[kk], sac[jj],
                                                          0, 0, 0);
      }

    // ---- scale (+ causal mask, last tile only), per-lane max ----
    float pv[4][4];
    float mt = NEGF;
    const bool last = (t == ntiles - 1);
    #pragma unroll
    for (int jj = 0; jj < 4; ++jj)
      #pragma unroll
      for (int r = 0; r < 4; ++r) {
        float s = sac[jj][r] * scale2;
        if (last) {
          int kcol = kv0 + jj * 16 + 4 * g + r;
          s = (kcol > qrow) ? NEGF : s;
        }
        pv[jj][r] = s;
        mt = fmaxf(mt, s);
      }
    // cross-g reduce (q is lane-local; k spread over lane groups of 16)
    mt = fmaxf(mt, __shfl_xor(mt, 16));
    mt = fmaxf(mt, __shfl_xor(mt, 32));

    float mnew = fmaxf(mrun, mt);
    float fac = exp2f(mrun - mnew);   // first tile: exp2(-huge) = 0
    mrun = mnew;

    float rs = 0.f;
    #pragma unroll
    for (int jj = 0; jj < 4; ++jj)
      #pragma unroll
      for (int r = 0; r < 4; ++r) {
        float p = exp2f(pv[jj][r] - mrun);  // masked: exp2(-huge)=0
        pv[jj][r] = p;
        rs += p;
      }
    lrun = lrun * fac + rs;   // lane-partial over this g-group's k; reduced at end
    #pragma unroll
    for (int j2 = 0; j2 < 4; ++j2)
      #pragma unroll
      for (int r = 0; r < 4; ++r)
        acc[j2][r] *= fac;

    // ---- pack P^T to bf16, store transposed (dword col = k/2, quad-swizzled) ----
    #pragma unroll
    for (int jj = 0; jj < 4; ++jj)
      #pragma unroll
      for (int rp = 0; rp < 2; ++rp) {
        unsigned w;
        asm("v_cvt_pk_bf16_f32 %0, %1, %2"
            : "=v"(w) : "v"(pv[jj][2 * rp]), "v"(pv[jj][2 * rp + 1]));
        int c = jj * 8 + g * 2 + rp;                       // k/2
        int addr = r16 * 32 + (((c >> 2) ^ (r16 & 7)) << 2) + (c & 3);
        Pld[wq][addr] = w;
      }

    // ---- ctx^T += V^T P  (pf = B-frag: lane q=r16, elems k) ----
    bf16x8 pf[2];
    #pragma unroll
    for (int half = 0; half < 2; ++half) {
      int c = half * 16 + g * 4;
      int addr = r16 * 32 + (((c >> 2) ^ (r16 & 7)) << 2);
      pf[half] = *(const bf16x8*)&Pld[wq][addr];
    }
    #pragma unroll
    for (int j2 = 0; j2 < 4; ++j2)
      #pragma unroll
      for (int half = 0; half < 2; ++half) {
        int dd = j2 * 16 + r16;
        bf16x8 vf = *(const bf16x8*)
            &Vs[cur][dd * 64 + (((half << 2) + g) ^ (dd & 7)) * 8];
        acc[j2] = __builtin_amdgcn_mfma_f32_16x16x32_bf16(vf, pf[half],
                                                          acc[j2], 0, 0, 0);
      }
    __syncthreads();   // drains prefetch (vmcnt) + all LDS reads (lgkm)
  }

  // total row-sum: combine the 4 g-group partials
  lrun += __shfl_xor(lrun, 16);
  lrun += __shfl_xor(lrun, 32);
  const float inv = 1.f / lrun;

  const int s = q0 + r16;
  #pragma unroll
  for (int j2 = 0; j2 < 4; ++j2)
    #pragma unroll
    for (int r = 0; r < 4; ++r) {
      int d = j2 * 16 + 4 * g + r;
      ctxb[((size_t)(b * SSX + s)) * DIMX + h * HDX + d] =
          (__bf16)(acc[j2][r] * inv);
    }
}

extern "C" void kernel_launch(void* const* d_in, const int* in_sizes, int n_in,
                              void* d_out, int out_size, void* d_ws,
                              size_t ws_size, hipStream_t stream) {
  const float* x  = (const float*)d_in[0];
  const float* Wq = (const float*)d_in[1];
  const float* bq = (const float*)d_in[2];
  const float* Wk = (const float*)d_in[3];
  const float* bk = (const float*)d_in[4];
  const float* Wv = (const float*)d_in[5];
  const float* bv = (const float*)d_in[6];
  const float* Wo = (const float*)d_in[7];
  const float* bo = (const float*)d_in[8];
  float* out = (float*)d_out;

  char* ws = (char*)d_ws;                       // needs 40 MB
  __bf16* xb    = (__bf16*)(ws);                // 8 MB, reused as ctxb later
  __bf16* wqkvT = (__bf16*)(ws + ((size_t)8  << 20));  // 6 MB
  __bf16* woT   = (__bf16*)(ws + ((size_t)14 << 20));  // 2 MB
  __bf16* qb    = (__bf16*)(ws + ((size_t)16 << 20));  // 8 MB
  __bf16* kb    = (__bf16*)(ws + ((size_t)24 << 20));  // 8 MB
  __bf16* vtb   = (__bf16*)(ws + ((size_t)32 << 20));  // 8 MB (V^T)
  __bf16* ctxb  = xb;   // x dead after QKV GEMM

  k_convert_x<<<4096, 256, 0, stream>>>(x, xb);
  k_transpose_w<<<dim3(256, 4), 256, 0, stream>>>(Wq, Wk, Wv, Wo, wqkvT, woT);
  k_gemm<0><<<dim3(32, 24), 256, 0, stream>>>(xb, wqkvT, bq, bk, bv,
                                              qb, kb, vtb, nullptr);
  k_attn<<<dim3(32, 32), 256, 0, stream>>>(qb, kb, vtb, ctxb);
  k_gemm<1><<<dim3(32, 8), 256, 0, stream>>>(ctxb, woT, bo, nullptr, nullptr,
                                             nullptr, nullptr, nullptr, out);
}

// Round 5
// 121.852 us; speedup vs baseline: 2.4595x; 1.0997x over previous
//
#include <hip/hip_runtime.h>
#include <hip/hip_bf16.h>
#include <math.h>

#define DIMX 1024
#define HEADSX 16
#define HDX 64
#define BBX 2
#define SSX 2048
#define MMX (BBX*SSX)   // 4096 rows

typedef __bf16 bf16x8 __attribute__((ext_vector_type(8)));
typedef __bf16 bf16x4 __attribute__((ext_vector_type(4)));
typedef float  f32x4  __attribute__((ext_vector_type(4)));

#define NEGF (-1e30f)

// async 16B global->LDS. LDS dest must be wave-uniform base; HW adds lane*16.
static __device__ __forceinline__ void gload16(const void* g, void* l) {
  __builtin_amdgcn_global_load_lds(
      (const __attribute__((address_space(1))) unsigned int*)g,
      (__attribute__((address_space(3))) unsigned int*)l, 16, 0, 0);
}

// ---------------- kernel 1: x fp32 -> bf16 (same layout) ----------------
__global__ __launch_bounds__(256) void k_convert_x(const float* __restrict__ x,
                                                   __bf16* __restrict__ xb) {
  int i = (blockIdx.x * 256 + threadIdx.x) * 4;
  float4 v = *(const float4*)&x[i];
  bf16x4 o = { (__bf16)v.x, (__bf16)v.y, (__bf16)v.z, (__bf16)v.w };
  *(bf16x4*)&xb[i] = o;
}

// ------------- kernel 2: W [K][N] fp32 -> W^T [N][K] bf16 ---------------
__global__ __launch_bounds__(256) void k_transpose_w(
    const float* __restrict__ Wq, const float* __restrict__ Wk,
    const float* __restrict__ Wv, const float* __restrict__ Wo,
    __bf16* __restrict__ wqkvT, __bf16* __restrict__ woT) {
  __shared__ __bf16 tile[64][65];
  const int mat = blockIdx.y;
  const float* src = (mat == 0) ? Wq : (mat == 1) ? Wk : (mat == 2) ? Wv : Wo;
  __bf16* dst = (mat < 3) ? (wqkvT + (size_t)mat * DIMX * DIMX) : woT;
  const int tx = blockIdx.x & 15, ty = blockIdx.x >> 4;
  const int k0 = ty * 64, n0 = tx * 64;
  #pragma unroll
  for (int rep = 0; rep < 16; ++rep) {
    int idx = rep * 256 + threadIdx.x;
    int r = idx >> 6, c = idx & 63;
    tile[r][c] = (__bf16)src[(size_t)(k0 + r) * DIMX + n0 + c];
  }
  __syncthreads();
  #pragma unroll
  for (int rep = 0; rep < 16; ++rep) {
    int idx = rep * 256 + threadIdx.x;
    int r = idx >> 6, c = idx & 63;           // r = local n, c = local k
    dst[(size_t)(n0 + r) * DIMX + k0 + c] = tile[c][r];
  }
}

// ---------------- kernels 3/5: bf16 GEMM, 128x128 tile, BK=32 ----------------
// C[m][n] = sum_k A[m][k]*Bt[n][k] (+bias). EPI=0: QKV scatter, EPI=1: fp32 out.
template<int EPI>
__global__ __launch_bounds__(256) void k_gemm(
    const __bf16* __restrict__ A,    // [M][1024]
    const __bf16* __restrict__ Bt,   // [N][1024]
    const float* __restrict__ b0, const float* __restrict__ b1,
    const float* __restrict__ b2,
    __bf16* __restrict__ qb, __bf16* __restrict__ kb, __bf16* __restrict__ vtb,
    float* __restrict__ outf) {
  constexpr int BK = 32, K = 1024;
  __shared__ __bf16 As[128 * BK];
  __shared__ __bf16 Bs[128 * BK];
  const int tid = threadIdx.x, lane = tid & 63, wave = tid >> 6;
  const int g = lane >> 4, r16 = lane & 15;
  const int wm = wave & 1, wn = wave >> 1;
  const int m0 = blockIdx.x * 128, n0 = blockIdx.y * 128;

  f32x4 acc[4][4] = {};

  for (int k0 = 0; k0 < K; k0 += BK) {
    __syncthreads();   // previous iteration's ds_reads done before overwrite
    #pragma unroll
    for (int i = 0; i < 2; ++i) {
      int c = wave * 64 + lane + 256 * i;       // chunk id (512 x 16B per tile)
      gload16(&A [(size_t)(m0 + (c >> 2)) * K + k0 + (c & 3) * 8],
              (char*)As + (size_t)(wave * 64 + 256 * i) * 16);
      gload16(&Bt[(size_t)(n0 + (c >> 2)) * K + k0 + (c & 3) * 8],
              (char*)Bs + (size_t)(wave * 64 + 256 * i) * 16);
    }
    __syncthreads();   // compiler drains vmcnt(0) before barrier
    bf16x8 af[4], bfr[4];
    #pragma unroll
    for (int i = 0; i < 4; ++i)
      af[i]  = *(const bf16x8*)&As[(wm * 64 + i * 16 + r16) * BK + g * 8];
    #pragma unroll
    for (int j = 0; j < 4; ++j)
      bfr[j] = *(const bf16x8*)&Bs[(wn * 64 + j * 16 + r16) * BK + g * 8];
    #pragma unroll
    for (int i = 0; i < 4; ++i)
      #pragma unroll
      for (int j = 0; j < 4; ++j)
        acc[i][j] = __builtin_amdgcn_mfma_f32_16x16x32_bf16(af[i], bfr[j],
                                                            acc[i][j], 0, 0, 0);
  }

  #pragma unroll
  for (int i = 0; i < 4; ++i) {
    #pragma unroll
    for (int j = 0; j < 4; ++j) {
      #pragma unroll
      for (int r = 0; r < 4; ++r) {
        int m = m0 + wm * 64 + i * 16 + 4 * g + r;   // C row = (lane>>4)*4+reg
        int n = n0 + wn * 64 + j * 16 + r16;         // C col = lane&15
        float v = acc[i][j][r];
        if constexpr (EPI == 0) {
          int proj = n >> 10, w = n & 1023, h = w >> 6, d = w & 63;
          const float* bp = (proj == 0) ? b0 : (proj == 1) ? b1 : b2;
          v += bp[w];
          int b = m >> 11, s = m & 2047, bh = b * HEADSX + h;
          if (proj == 0)      qb [((size_t)bh * SSX + s) * HDX + d] = (__bf16)v;
          else if (proj == 1) kb [((size_t)bh * SSX + s) * HDX + d] = (__bf16)v;
          else                vtb[((size_t)bh * HDX + d) * SSX + s] = (__bf16)v;
        } else {
          outf[(size_t)m * DIMX + n] = v + b0[n];
        }
      }
    }
  }
}

// ---------------- kernel 4: causal flash attention, paired q-tiles ----------------
// Complementary pairing: block p handles q-tile qL=p (ntL=p+1 kv-tiles) AND
// q-tile qH=31-p (ntH=32-p) -> every block does exactly 33 kv-tiles (uniform,
// no tail). Each wave owns 16 rows of BOTH sub-tiles; K/V staged once per
// kv-tile, shared. Swapped-operand MFMA (S^T, ctx^T) as before. 512 blocks,
// XCD-chunked bh mapping (4 heads/XCD -> 1MB K/V per L2).
__global__ __launch_bounds__(256, 2) void k_attn(
    const __bf16* __restrict__ qb, const __bf16* __restrict__ kb,
    const __bf16* __restrict__ vtb, __bf16* __restrict__ ctxb) {
  const int tid = threadIdx.x;
  const int lane = tid & 63, wq = tid >> 6;
  const int g = lane >> 4, r16 = lane & 15;

  // XCD-chunked mapping: id%8 = XCD; 4 consecutive bh per XCD.
  const int id = blockIdx.x;
  const int xcd = id & 7, idx = id >> 3;
  const int bh = xcd * 4 + (idx & 3);
  const int p  = idx >> 2;                 // pair index 0..15
  const int b = bh >> 4, h = bh & 15;

  const int ntL = p + 1, ntH = 32 - p;     // ntL <= 16 < ntH
  const int q0L = p * 64 + wq * 16;
  const int q0H = (31 - p) * 64 + wq * 16;

  const __bf16* Q  = qb  + (size_t)bh * SSX * HDX;
  const __bf16* Kp = kb  + (size_t)bh * SSX * HDX;
  const __bf16* Vt = vtb + (size_t)bh * HDX * SSX;

  __shared__ __bf16 Ks[2][64 * 64];    // 2 x 8 KB
  __shared__ __bf16 Vs[2][64 * 64];    // 2 x 8 KB
  __shared__ unsigned Pld[4][512];     // per-wave P^T scratch, 2 KB

  bf16x8 qfL[2], qfH[2];
  qfL[0] = *(const bf16x8*)&Q[(size_t)(q0L + r16) * HDX + g * 8];
  qfL[1] = *(const bf16x8*)&Q[(size_t)(q0L + r16) * HDX + 32 + g * 8];
  qfH[0] = *(const bf16x8*)&Q[(size_t)(q0H + r16) * HDX + g * 8];
  qfH[1] = *(const bf16x8*)&Q[(size_t)(q0H + r16) * HDX + 32 + g * 8];

  f32x4 accL[4] = {}, accH[4] = {};    // ctx^T: acc[j2][r]=ctx[d=j2*16+4g+r][q=r16]
  float mrunL = NEGF, lrunL = 0.f;
  float mrunH = NEGF, lrunH = 0.f;

  const float scale2 = 0.18033688011112042f;       // (1/8) * log2(e)

  // stage tile t (64 kv x 64) of K and V into buf. 512 chunks each, 2/thread.
  // LDS chunk (r, cb) receives global chunk (r, cb ^ (r&7))  [read undoes it]
  auto STAGE = [&](int buf, int t) {
    const int kv0 = t * 64;
    #pragma unroll
    for (int i = 0; i < 2; ++i) {
      int c = tid + 256 * i;
      int r = c >> 3;
      int cb = (c & 7) ^ (r & 7);
      gload16(&Kp[(size_t)(kv0 + r) * HDX + cb * 8],
              (char*)Ks[buf] + (size_t)(wq * 64 + 256 * i) * 16);
      gload16(&Vt[(size_t)r * SSX + kv0 + cb * 8],
              (char*)Vs[buf] + (size_t)(wq * 64 + 256 * i) * 16);
    }
  };

  // one 16q x 64k sub-tile step against the staged kv-tile
  auto SUBTILE = [&](const bf16x8* qf, f32x4* acc, float& mrun, float& lrun,
                     int qrow, bool last, int kv0, int cur) {
    // ---- S^T = K Q^T: sac[jj][r] = S[k=kv0+16jj+4g+r][q=r16] ----
    f32x4 sac[4] = {};
    __builtin_amdgcn_s_setprio(1);
    #pragma unroll
    for (int kk = 0; kk < 2; ++kk)
      #pragma unroll
      for (int jj = 0; jj < 4; ++jj) {
        int rr = jj * 16 + r16;
        bf16x8 kf = *(const bf16x8*)
            &Ks[cur][rr * 64 + (((kk << 2) + g) ^ (rr & 7)) * 8];
        sac[jj] = __builtin_amdgcn_mfma_f32_16x16x32_bf16(kf, qf[kk], sac[jj],
                                                          0, 0, 0);
      }
    __builtin_amdgcn_s_setprio(0);

    // ---- scale (+ causal mask on the diagonal tile), per-lane max ----
    float pv[4][4];
    float mt = NEGF;
    #pragma unroll
    for (int jj = 0; jj < 4; ++jj)
      #pragma unroll
      for (int r = 0; r < 4; ++r) {
        float s = sac[jj][r] * scale2;
        if (last) {
          int kcol = kv0 + jj * 16 + 4 * g + r;
          s = (kcol > qrow) ? NEGF : s;
        }
        pv[jj][r] = s;
        mt = fmaxf(mt, s);
      }
    mt = fmaxf(mt, __shfl_xor(mt, 16));
    mt = fmaxf(mt, __shfl_xor(mt, 32));

    float mnew = fmaxf(mrun, mt);
    float fac = exp2f(mrun - mnew);
    mrun = mnew;

    float rs = 0.f;
    #pragma unroll
    for (int jj = 0; jj < 4; ++jj)
      #pragma unroll
      for (int r = 0; r < 4; ++r) {
        float px = exp2f(pv[jj][r] - mrun);
        pv[jj][r] = px;
        rs += px;
      }
    lrun = lrun * fac + rs;   // lane-partial; cross-g reduced at end
    #pragma unroll
    for (int j2 = 0; j2 < 4; ++j2)
      #pragma unroll
      for (int r = 0; r < 4; ++r)
        acc[j2][r] *= fac;

    // ---- pack P^T to bf16, store transposed (dword col = k/2, quad-swizzled) ----
    #pragma unroll
    for (int jj = 0; jj < 4; ++jj)
      #pragma unroll
      for (int rp = 0; rp < 2; ++rp) {
        unsigned w;
        asm("v_cvt_pk_bf16_f32 %0, %1, %2"
            : "=v"(w) : "v"(pv[jj][2 * rp]), "v"(pv[jj][2 * rp + 1]));
        int c = jj * 8 + g * 2 + rp;                       // k/2
        int addr = r16 * 32 + (((c >> 2) ^ (r16 & 7)) << 2) + (c & 3);
        Pld[wq][addr] = w;
      }

    // ---- ctx^T += V^T P ----
    bf16x8 pf[2];
    #pragma unroll
    for (int half = 0; half < 2; ++half) {
      int c = half * 16 + g * 4;
      int addr = r16 * 32 + (((c >> 2) ^ (r16 & 7)) << 2);
      pf[half] = *(const bf16x8*)&Pld[wq][addr];
    }
    __builtin_amdgcn_s_setprio(1);
    #pragma unroll
    for (int j2 = 0; j2 < 4; ++j2)
      #pragma unroll
      for (int half = 0; half < 2; ++half) {
        int dd = j2 * 16 + r16;
        bf16x8 vf = *(const bf16x8*)
            &Vs[cur][dd * 64 + (((half << 2) + g) ^ (dd & 7)) * 8];
        acc[j2] = __builtin_amdgcn_mfma_f32_16x16x32_bf16(vf, pf[half],
                                                          acc[j2], 0, 0, 0);
      }
    __builtin_amdgcn_s_setprio(0);
  };

  STAGE(0, 0);
  __syncthreads();

  for (int t = 0; t < ntH; ++t) {
    const int cur = t & 1;
    if (t + 1 < ntH) STAGE(cur ^ 1, t + 1);   // async prefetch next tile
    const int kv0 = t * 64;

    SUBTILE(qfH, accH, mrunH, lrunH, q0H + r16, t == ntH - 1, kv0, cur);
    if (t < ntL)
      SUBTILE(qfL, accL, mrunL, lrunL, q0L + r16, t == ntL - 1, kv0, cur);

    __syncthreads();   // drains prefetch (vmcnt) + all LDS reads (lgkm)
  }

  auto EPIL = [&](f32x4* acc, float lrun, int q0) {
    lrun += __shfl_xor(lrun, 16);
    lrun += __shfl_xor(lrun, 32);
    const float inv = 1.f / lrun;
    const int s = q0 + r16;
    #pragma unroll
    for (int j2 = 0; j2 < 4; ++j2)
      #pragma unroll
      for (int r = 0; r < 4; ++r) {
        int d = j2 * 16 + 4 * g + r;
        ctxb[((size_t)(b * SSX + s)) * DIMX + h * HDX + d] =
            (__bf16)(acc[j2][r] * inv);
      }
  };
  EPIL(accH, lrunH, q0H);
  EPIL(accL, lrunL, q0L);
}

extern "C" void kernel_launch(void* const* d_in, const int* in_sizes, int n_in,
                              void* d_out, int out_size, void* d_ws,
                              size_t ws_size, hipStream_t stream) {
  const float* x  = (const float*)d_in[0];
  const float* Wq = (const float*)d_in[1];
  const float* bq = (const float*)d_in[2];
  const float* Wk = (const float*)d_in[3];
  const float* bk = (const float*)d_in[4];
  const float* Wv = (const float*)d_in[5];
  const float* bv = (const float*)d_in[6];
  const float* Wo = (const float*)d_in[7];
  const float* bo = (const float*)d_in[8];
  float* out = (float*)d_out;

  char* ws = (char*)d_ws;                       // needs 40 MB
  __bf16* xb    = (__bf16*)(ws);                // 8 MB, reused as ctxb later
  __bf16* wqkvT = (__bf16*)(ws + ((size_t)8  << 20));  // 6 MB
  __bf16* woT   = (__bf16*)(ws + ((size_t)14 << 20));  // 2 MB
  __bf16* qb    = (__bf16*)(ws + ((size_t)16 << 20));  // 8 MB
  __bf16* kb    = (__bf16*)(ws + ((size_t)24 << 20));  // 8 MB
  __bf16* vtb   = (__bf16*)(ws + ((size_t)32 << 20));  // 8 MB (V^T)
  __bf16* ctxb  = xb;   // x dead after QKV GEMM

  k_convert_x<<<4096, 256, 0, stream>>>(x, xb);
  k_transpose_w<<<dim3(256, 4), 256, 0, stream>>>(Wq, Wk, Wv, Wo, wqkvT, woT);
  k_gemm<0><<<dim3(32, 24), 256, 0, stream>>>(xb, wqkvT, bq, bk, bv,
                                              qb, kb, vtb, nullptr);
  k_attn<<<512, 256, 0, stream>>>(qb, kb, vtb, ctxb);
  k_gemm<1><<<dim3(32, 8), 256, 0, stream>>>(ctxb, woT, bo, nullptr, nullptr,
                                             nullptr, nullptr, nullptr, out);
}

// Round 6
// 118.474 us; speedup vs baseline: 2.5297x; 1.0285x over previous
//
#include <hip/hip_runtime.h>
#include <hip/hip_bf16.h>
#include <math.h>

#define DIMX 1024
#define HEADSX 16
#define HDX 64
#define BBX 2
#define SSX 2048
#define MMX (BBX*SSX)   // 4096 rows

typedef __bf16 bf16x8 __attribute__((ext_vector_type(8)));
typedef __bf16 bf16x4 __attribute__((ext_vector_type(4)));
typedef float  f32x4  __attribute__((ext_vector_type(4)));

#define NEGF (-1e30f)
#define QSCALE 0.18033688011112042f   // (1/sqrt(64)) * log2(e), folded into Q

// async 16B global->LDS. LDS dest must be wave-uniform base; HW adds lane*16.
static __device__ __forceinline__ void gload16(const void* g, void* l) {
  __builtin_amdgcn_global_load_lds(
      (const __attribute__((address_space(1))) unsigned int*)g,
      (__attribute__((address_space(3))) unsigned int*)l, 16, 0, 0);
}

// ---------------- kernel 1: x fp32 -> bf16 (same layout) ----------------
__global__ __launch_bounds__(256) void k_convert_x(const float* __restrict__ x,
                                                   __bf16* __restrict__ xb) {
  int i = (blockIdx.x * 256 + threadIdx.x) * 4;
  float4 v = *(const float4*)&x[i];
  bf16x4 o = { (__bf16)v.x, (__bf16)v.y, (__bf16)v.z, (__bf16)v.w };
  *(bf16x4*)&xb[i] = o;
}

// ------------- kernel 2: W [K][N] fp32 -> W^T [N][K] bf16 ---------------
__global__ __launch_bounds__(256) void k_transpose_w(
    const float* __restrict__ Wq, const float* __restrict__ Wk,
    const float* __restrict__ Wv, const float* __restrict__ Wo,
    __bf16* __restrict__ wqkvT, __bf16* __restrict__ woT) {
  __shared__ __bf16 tile[64][65];
  const int mat = blockIdx.y;
  const float* src = (mat == 0) ? Wq : (mat == 1) ? Wk : (mat == 2) ? Wv : Wo;
  __bf16* dst = (mat < 3) ? (wqkvT + (size_t)mat * DIMX * DIMX) : woT;
  const int tx = blockIdx.x & 15, ty = blockIdx.x >> 4;
  const int k0 = ty * 64, n0 = tx * 64;
  #pragma unroll
  for (int rep = 0; rep < 16; ++rep) {
    int idx = rep * 256 + threadIdx.x;
    int r = idx >> 6, c = idx & 63;
    tile[r][c] = (__bf16)src[(size_t)(k0 + r) * DIMX + n0 + c];
  }
  __syncthreads();
  #pragma unroll
  for (int rep = 0; rep < 16; ++rep) {
    int idx = rep * 256 + threadIdx.x;
    int r = idx >> 6, c = idx & 63;           // r = local n, c = local k
    dst[(size_t)(n0 + r) * DIMX + k0 + c] = tile[c][r];
  }
}

// ---------------- kernel 3: QKV GEMM, 128x128 tile, BK=32 ----------------
// C[m][n] = A[m][:] . Bt[n][:] + bias; scatter epilogue writes Q (pre-scaled
// by QSCALE), K as [B,H,S,hd], V transposed [B,H,hd,S].
// m-chunked XCD mapping: each XCD owns 4 consecutive m-rows (A panel 1MB -> L2).
__global__ __launch_bounds__(256) void k_gemm_qkv(
    const __bf16* __restrict__ A,    // [4096][1024]
    const __bf16* __restrict__ Bt,   // [3072][1024]
    const float* __restrict__ b0, const float* __restrict__ b1,
    const float* __restrict__ b2,
    __bf16* __restrict__ qb, __bf16* __restrict__ kb, __bf16* __restrict__ vtb) {
  constexpr int BK = 32, K = 1024;
  __shared__ __bf16 As[128 * BK];
  __shared__ __bf16 Bs[128 * BK];
  const int tid = threadIdx.x, lane = tid & 63, wave = tid >> 6;
  const int g = lane >> 4, r16 = lane & 15;
  const int wm = wave & 1, wn = wave >> 1;
  const int id = blockIdx.x;                 // 768 blocks = 8 XCD x 96
  const int xcd = id & 7, j96 = id >> 3;
  const int m0 = (xcd * 4 + (j96 & 3)) * 128;   // 32 m-tiles
  const int n0 = (j96 >> 2) * 128;              // 24 n-tiles

  f32x4 acc[4][4] = {};

  for (int k0 = 0; k0 < K; k0 += BK) {
    __syncthreads();   // previous iteration's ds_reads done before overwrite
    #pragma unroll
    for (int i = 0; i < 2; ++i) {
      int c = wave * 64 + lane + 256 * i;       // chunk id (512 x 16B per tile)
      gload16(&A [(size_t)(m0 + (c >> 2)) * K + k0 + (c & 3) * 8],
              (char*)As + (size_t)(wave * 64 + 256 * i) * 16);
      gload16(&Bt[(size_t)(n0 + (c >> 2)) * K + k0 + (c & 3) * 8],
              (char*)Bs + (size_t)(wave * 64 + 256 * i) * 16);
    }
    __syncthreads();   // compiler drains vmcnt(0) before barrier
    bf16x8 af[4], bfr[4];
    #pragma unroll
    for (int i = 0; i < 4; ++i)
      af[i]  = *(const bf16x8*)&As[(wm * 64 + i * 16 + r16) * BK + g * 8];
    #pragma unroll
    for (int j = 0; j < 4; ++j)
      bfr[j] = *(const bf16x8*)&Bs[(wn * 64 + j * 16 + r16) * BK + g * 8];
    #pragma unroll
    for (int i = 0; i < 4; ++i)
      #pragma unroll
      for (int j = 0; j < 4; ++j)
        acc[i][j] = __builtin_amdgcn_mfma_f32_16x16x32_bf16(af[i], bfr[j],
                                                            acc[i][j], 0, 0, 0);
  }

  #pragma unroll
  for (int i = 0; i < 4; ++i) {
    #pragma unroll
    for (int j = 0; j < 4; ++j) {
      #pragma unroll
      for (int r = 0; r < 4; ++r) {
        int m = m0 + wm * 64 + i * 16 + 4 * g + r;   // C row = (lane>>4)*4+reg
        int n = n0 + wn * 64 + j * 16 + r16;         // C col = lane&15
        float v = acc[i][j][r];
        int proj = n >> 10, w = n & 1023, h = w >> 6, d = w & 63;
        const float* bp = (proj == 0) ? b0 : (proj == 1) ? b1 : b2;
        v += bp[w];
        int b = m >> 11, s = m & 2047, bh = b * HEADSX + h;
        if (proj == 0)      qb [((size_t)bh * SSX + s) * HDX + d] =
                                (__bf16)(v * QSCALE);
        else if (proj == 1) kb [((size_t)bh * SSX + s) * HDX + d] = (__bf16)v;
        else                vtb[((size_t)bh * HDX + d) * SSX + s] = (__bf16)v;
      }
    }
  }
}

// ---------------- kernel 5: output GEMM, 64x64 tile (occupancy) ----------------
// 1024 blocks = 4/CU (the 128x128 version gave 256 blocks = 1/CU, latency-bound).
__global__ __launch_bounds__(256) void k_gemm_out(
    const __bf16* __restrict__ A,    // ctx [4096][1024]
    const __bf16* __restrict__ Bt,   // WoT [1024][1024]
    const float* __restrict__ bias, float* __restrict__ outf) {
  constexpr int BK = 32, K = 1024;
  __shared__ __bf16 As[64 * BK];     // 4 KB
  __shared__ __bf16 Bs[64 * BK];     // 4 KB
  const int tid = threadIdx.x, lane = tid & 63, wave = tid >> 6;
  const int g = lane >> 4, r16 = lane & 15;
  const int wm = wave & 1, wn = wave >> 1;
  const int id = blockIdx.x;                 // 1024 blocks = 8 XCD x 128
  const int xcd = id & 7, j128 = id >> 3;
  const int m0 = (xcd * 8 + (j128 & 7)) * 64;   // 64 m-tiles
  const int n0 = (j128 >> 3) * 64;              // 16 n-tiles

  f32x4 acc[2][2] = {};

  for (int k0 = 0; k0 < K; k0 += BK) {
    __syncthreads();
    {
      int c = tid;                           // 256 chunks per matrix, 1/thread
      gload16(&A [(size_t)(m0 + (c >> 2)) * K + k0 + (c & 3) * 8],
              (char*)As + (size_t)(wave * 64) * 16);
      gload16(&Bt[(size_t)(n0 + (c >> 2)) * K + k0 + (c & 3) * 8],
              (char*)Bs + (size_t)(wave * 64) * 16);
    }
    __syncthreads();
    bf16x8 af[2], bfr[2];
    #pragma unroll
    for (int i = 0; i < 2; ++i)
      af[i]  = *(const bf16x8*)&As[(wm * 32 + i * 16 + r16) * BK + g * 8];
    #pragma unroll
    for (int j = 0; j < 2; ++j)
      bfr[j] = *(const bf16x8*)&Bs[(wn * 32 + j * 16 + r16) * BK + g * 8];
    #pragma unroll
    for (int i = 0; i < 2; ++i)
      #pragma unroll
      for (int j = 0; j < 2; ++j)
        acc[i][j] = __builtin_amdgcn_mfma_f32_16x16x32_bf16(af[i], bfr[j],
                                                            acc[i][j], 0, 0, 0);
  }

  #pragma unroll
  for (int i = 0; i < 2; ++i)
    #pragma unroll
    for (int j = 0; j < 2; ++j)
      #pragma unroll
      for (int r = 0; r < 4; ++r) {
        int m = m0 + wm * 32 + i * 16 + 4 * g + r;
        int n = n0 + wn * 32 + j * 16 + r16;
        outf[(size_t)m * DIMX + n] = acc[i][j][r] + bias[n];
      }
}

// ---------------- kernel 4: causal flash attention, paired q-tiles ----------------
// Complementary pairing: block p handles q-tile qL=p (ntL=p+1 kv-tiles) AND
// q-tile qH=31-p (ntH=32-p) -> every block does exactly 33 kv-tiles (uniform).
// Swapped-operand MFMA (S^T, ctx^T); Q pre-scaled by QSCALE in the QKV GEMM;
// T13 defer-max skips the rescale pass when the running max doesn't grow.
__global__ __launch_bounds__(256, 2) void k_attn(
    const __bf16* __restrict__ qb, const __bf16* __restrict__ kb,
    const __bf16* __restrict__ vtb, __bf16* __restrict__ ctxb) {
  const int tid = threadIdx.x;
  const int lane = tid & 63, wq = tid >> 6;
  const int g = lane >> 4, r16 = lane & 15;

  // XCD-chunked mapping: id%8 = XCD; 4 consecutive bh per XCD.
  const int id = blockIdx.x;
  const int xcd = id & 7, idx = id >> 3;
  const int bh = xcd * 4 + (idx & 3);
  const int p  = idx >> 2;                 // pair index 0..15
  const int b = bh >> 4, h = bh & 15;

  const int ntL = p + 1, ntH = 32 - p;     // ntL <= 16 < ntH
  const int q0L = p * 64 + wq * 16;
  const int q0H = (31 - p) * 64 + wq * 16;

  const __bf16* Q  = qb  + (size_t)bh * SSX * HDX;
  const __bf16* Kp = kb  + (size_t)bh * SSX * HDX;
  const __bf16* Vt = vtb + (size_t)bh * HDX * SSX;

  __shared__ __bf16 Ks[2][64 * 64];    // 2 x 8 KB
  __shared__ __bf16 Vs[2][64 * 64];    // 2 x 8 KB
  __shared__ unsigned Pld[4][512];     // per-wave P^T scratch, 2 KB

  bf16x8 qfL[2], qfH[2];
  qfL[0] = *(const bf16x8*)&Q[(size_t)(q0L + r16) * HDX + g * 8];
  qfL[1] = *(const bf16x8*)&Q[(size_t)(q0L + r16) * HDX + 32 + g * 8];
  qfH[0] = *(const bf16x8*)&Q[(size_t)(q0H + r16) * HDX + g * 8];
  qfH[1] = *(const bf16x8*)&Q[(size_t)(q0H + r16) * HDX + 32 + g * 8];

  f32x4 accL[4] = {}, accH[4] = {};    // ctx^T: acc[j2][r]=ctx[d=j2*16+4g+r][q=r16]
  float mrunL = NEGF, lrunL = 0.f;
  float mrunH = NEGF, lrunH = 0.f;

  // stage tile t (64 kv x 64) of K and V into buf. 512 chunks each, 2/thread.
  // LDS chunk (r, cb) receives global chunk (r, cb ^ (r&7))  [read undoes it]
  auto STAGE = [&](int buf, int t) {
    const int kv0 = t * 64;
    #pragma unroll
    for (int i = 0; i < 2; ++i) {
      int c = tid + 256 * i;
      int r = c >> 3;
      int cb = (c & 7) ^ (r & 7);
      gload16(&Kp[(size_t)(kv0 + r) * HDX + cb * 8],
              (char*)Ks[buf] + (size_t)(wq * 64 + 256 * i) * 16);
      gload16(&Vt[(size_t)r * SSX + kv0 + cb * 8],
              (char*)Vs[buf] + (size_t)(wq * 64 + 256 * i) * 16);
    }
  };

  // one 16q x 64k sub-tile step against the staged kv-tile
  auto SUBTILE = [&](const bf16x8* qf, f32x4* acc, float& mrun, float& lrun,
                     int qrow, bool last, int kv0, int cur) {
    // ---- S^T = K Q^T: sac[jj][r] = S[k=kv0+16jj+4g+r][q=r16] (pre-scaled) ----
    f32x4 sac[4] = {};
    __builtin_amdgcn_s_setprio(1);
    #pragma unroll
    for (int kk = 0; kk < 2; ++kk)
      #pragma unroll
      for (int jj = 0; jj < 4; ++jj) {
        int rr = jj * 16 + r16;
        bf16x8 kf = *(const bf16x8*)
            &Ks[cur][rr * 64 + (((kk << 2) + g) ^ (rr & 7)) * 8];
        sac[jj] = __builtin_amdgcn_mfma_f32_16x16x32_bf16(kf, qf[kk], sac[jj],
                                                          0, 0, 0);
      }
    __builtin_amdgcn_s_setprio(0);

    // ---- causal mask (diagonal tile only), per-lane max ----
    float pv[4][4];
    float mt = NEGF;
    #pragma unroll
    for (int jj = 0; jj < 4; ++jj)
      #pragma unroll
      for (int r = 0; r < 4; ++r) {
        float s = sac[jj][r];
        if (last) {
          int kcol = kv0 + jj * 16 + 4 * g + r;
          s = (kcol > qrow) ? NEGF : s;
        }
        pv[jj][r] = s;
        mt = fmaxf(mt, s);
      }
    mt = fmaxf(mt, __shfl_xor(mt, 16));
    mt = fmaxf(mt, __shfl_xor(mt, 32));

    // T13 defer-max: only rescale when the wave's running max grew.
    // Skipping is exact here: mt <= mrun wave-wide => all P <= 1.
    if (__any(mt > mrun)) {
      float mnew = fmaxf(mrun, mt);
      float fac = exp2f(mrun - mnew);
      mrun = mnew;
      lrun *= fac;
      #pragma unroll
      for (int j2 = 0; j2 < 4; ++j2)
        #pragma unroll
        for (int r = 0; r < 4; ++r)
          acc[j2][r] *= fac;
    }

    float rs = 0.f;
    #pragma unroll
    for (int jj = 0; jj < 4; ++jj)
      #pragma unroll
      for (int r = 0; r < 4; ++r) {
        float px = exp2f(pv[jj][r] - mrun);
        pv[jj][r] = px;
        rs += px;
      }
    lrun += rs;   // lane-partial; cross-g reduced at end

    // ---- pack P^T to bf16, store transposed (dword col = k/2, quad-swizzled) ----
    #pragma unroll
    for (int jj = 0; jj < 4; ++jj)
      #pragma unroll
      for (int rp = 0; rp < 2; ++rp) {
        unsigned w;
        asm("v_cvt_pk_bf16_f32 %0, %1, %2"
            : "=v"(w) : "v"(pv[jj][2 * rp]), "v"(pv[jj][2 * rp + 1]));
        int c = jj * 8 + g * 2 + rp;                       // k/2
        int addr = r16 * 32 + (((c >> 2) ^ (r16 & 7)) << 2) + (c & 3);
        Pld[wq][addr] = w;
      }

    // ---- ctx^T += V^T P ----
    bf16x8 pf[2];
    #pragma unroll
    for (int half = 0; half < 2; ++half) {
      int c = half * 16 + g * 4;
      int addr = r16 * 32 + (((c >> 2) ^ (r16 & 7)) << 2);
      pf[half] = *(const bf16x8*)&Pld[wq][addr];
    }
    __builtin_amdgcn_s_setprio(1);
    #pragma unroll
    for (int j2 = 0; j2 < 4; ++j2)
      #pragma unroll
      for (int half = 0; half < 2; ++half) {
        int dd = j2 * 16 + r16;
        bf16x8 vf = *(const bf16x8*)
            &Vs[cur][dd * 64 + (((half << 2) + g) ^ (dd & 7)) * 8];
        acc[j2] = __builtin_amdgcn_mfma_f32_16x16x32_bf16(vf, pf[half],
                                                          acc[j2], 0, 0, 0);
      }
    __builtin_amdgcn_s_setprio(0);
  };

  STAGE(0, 0);
  __syncthreads();

  for (int t = 0; t < ntH; ++t) {
    const int cur = t & 1;
    if (t + 1 < ntH) STAGE(cur ^ 1, t + 1);   // async prefetch next tile
    const int kv0 = t * 64;

    SUBTILE(qfH, accH, mrunH, lrunH, q0H + r16, t == ntH - 1, kv0, cur);
    if (t < ntL)
      SUBTILE(qfL, accL, mrunL, lrunL, q0L + r16, t == ntL - 1, kv0, cur);

    __syncthreads();   // drains prefetch (vmcnt) + all LDS reads (lgkm)
  }

  auto EPIL = [&](f32x4* acc, float lrun, int q0) {
    lrun += __shfl_xor(lrun, 16);
    lrun += __shfl_xor(lrun, 32);
    const float inv = 1.f / lrun;
    const int s = q0 + r16;
    #pragma unroll
    for (int j2 = 0; j2 < 4; ++j2)
      #pragma unroll
      for (int r = 0; r < 4; ++r) {
        int d = j2 * 16 + 4 * g + r;
        ctxb[((size_t)(b * SSX + s)) * DIMX + h * HDX + d] =
            (__bf16)(acc[j2][r] * inv);
      }
  };
  EPIL(accH, lrunH, q0H);
  EPIL(accL, lrunL, q0L);
}

extern "C" void kernel_launch(void* const* d_in, const int* in_sizes, int n_in,
                              void* d_out, int out_size, void* d_ws,
                              size_t ws_size, hipStream_t stream) {
  const float* x  = (const float*)d_in[0];
  const float* Wq = (const float*)d_in[1];
  const float* bq = (const float*)d_in[2];
  const float* Wk = (const float*)d_in[3];
  const float* bk = (const float*)d_in[4];
  const float* Wv = (const float*)d_in[5];
  const float* bv = (const float*)d_in[6];
  const float* Wo = (const float*)d_in[7];
  const float* bo = (const float*)d_in[8];
  float* out = (float*)d_out;

  char* ws = (char*)d_ws;                       // needs 40 MB
  __bf16* xb    = (__bf16*)(ws);                // 8 MB, reused as ctxb later
  __bf16* wqkvT = (__bf16*)(ws + ((size_t)8  << 20));  // 6 MB
  __bf16* woT   = (__bf16*)(ws + ((size_t)14 << 20));  // 2 MB
  __bf16* qb    = (__bf16*)(ws + ((size_t)16 << 20));  // 8 MB
  __bf16* kb    = (__bf16*)(ws + ((size_t)24 << 20));  // 8 MB
  __bf16* vtb   = (__bf16*)(ws + ((size_t)32 << 20));  // 8 MB (V^T)
  __bf16* ctxb  = xb;   // x dead after QKV GEMM

  k_convert_x<<<4096, 256, 0, stream>>>(x, xb);
  k_transpose_w<<<dim3(256, 4), 256, 0, stream>>>(Wq, Wk, Wv, Wo, wqkvT, woT);
  k_gemm_qkv<<<768, 256, 0, stream>>>(xb, wqkvT, bq, bk, bv, qb, kb, vtb);
  k_attn<<<512, 256, 0, stream>>>(qb, kb, vtb, ctxb);
  k_gemm_out<<<1024, 256, 0, stream>>>(ctxb, woT, bo, out);
}

// Round 7
// 117.492 us; speedup vs baseline: 2.5508x; 1.0084x over previous
//
#include <hip/hip_runtime.h>
#include <hip/hip_bf16.h>
#include <math.h>

#define DIMX 1024
#define HEADSX 16
#define HDX 64
#define BBX 2
#define SSX 2048
#define MMX (BBX*SSX)   // 4096 rows

typedef __bf16 bf16x8 __attribute__((ext_vector_type(8)));
typedef __bf16 bf16x4 __attribute__((ext_vector_type(4)));
typedef float  f32x4  __attribute__((ext_vector_type(4)));

#define NEGF (-1e30f)
#define QSCALE 0.18033688011112042f   // (1/sqrt(64)) * log2(e), folded into Q

template<bool B> struct BoolC { static constexpr bool value = B; };

// async 16B global->LDS. LDS dest must be wave-uniform base; HW adds lane*16.
static __device__ __forceinline__ void gload16(const void* g, void* l) {
  __builtin_amdgcn_global_load_lds(
      (const __attribute__((address_space(1))) unsigned int*)g,
      (__attribute__((address_space(3))) unsigned int*)l, 16, 0, 0);
}

// ------- kernel 1: fused prep: x fp32->bf16  +  W transpose->bf16 -------
// blocks [0,4096): x convert; [4096,5120): W transpose (4 mats x 256 tiles)
__global__ __launch_bounds__(256) void k_prep(
    const float* __restrict__ x, const float* __restrict__ Wq,
    const float* __restrict__ Wk, const float* __restrict__ Wv,
    const float* __restrict__ Wo, __bf16* __restrict__ xb,
    __bf16* __restrict__ wqkvT, __bf16* __restrict__ woT) {
  const int bid = blockIdx.x;
  if (bid < 4096) {
    int i = (bid * 256 + threadIdx.x) * 4;
    float4 v = *(const float4*)&x[i];
    bf16x4 o = { (__bf16)v.x, (__bf16)v.y, (__bf16)v.z, (__bf16)v.w };
    *(bf16x4*)&xb[i] = o;
    return;
  }
  __shared__ __bf16 tile[64][65];
  const int wb = bid - 4096;
  const int mat = wb >> 8, t8 = wb & 255;
  const float* src = (mat == 0) ? Wq : (mat == 1) ? Wk : (mat == 2) ? Wv : Wo;
  __bf16* dst = (mat < 3) ? (wqkvT + (size_t)mat * DIMX * DIMX) : woT;
  const int tx = t8 & 15, ty = t8 >> 4;
  const int k0 = ty * 64, n0 = tx * 64;
  #pragma unroll
  for (int rep = 0; rep < 16; ++rep) {
    int idx = rep * 256 + threadIdx.x;
    int r = idx >> 6, c = idx & 63;
    tile[r][c] = (__bf16)src[(size_t)(k0 + r) * DIMX + n0 + c];
  }
  __syncthreads();
  #pragma unroll
  for (int rep = 0; rep < 16; ++rep) {
    int idx = rep * 256 + threadIdx.x;
    int r = idx >> 6, c = idx & 63;           // r = local n, c = local k
    dst[(size_t)(n0 + r) * DIMX + k0 + c] = tile[c][r];
  }
}

// ---------------- kernel 3: QKV GEMM, 128x128 tile, BK=32 ----------------
// C[m][n] = A[m][:] . Bt[n][:] + bias; scatter epilogue writes Q (pre-scaled
// by QSCALE), K as [B,H,S,hd], V transposed [B,H,hd,S].
// m-chunked XCD mapping: each XCD owns 4 consecutive m-rows (A panel 1MB -> L2).
__global__ __launch_bounds__(256) void k_gemm_qkv(
    const __bf16* __restrict__ A,    // [4096][1024]
    const __bf16* __restrict__ Bt,   // [3072][1024]
    const float* __restrict__ b0, const float* __restrict__ b1,
    const float* __restrict__ b2,
    __bf16* __restrict__ qb, __bf16* __restrict__ kb, __bf16* __restrict__ vtb) {
  constexpr int BK = 32, K = 1024;
  __shared__ __bf16 As[128 * BK];
  __shared__ __bf16 Bs[128 * BK];
  const int tid = threadIdx.x, lane = tid & 63, wave = tid >> 6;
  const int g = lane >> 4, r16 = lane & 15;
  const int wm = wave & 1, wn = wave >> 1;
  const int id = blockIdx.x;                 // 768 blocks = 8 XCD x 96
  const int xcd = id & 7, j96 = id >> 3;
  const int m0 = (xcd * 4 + (j96 & 3)) * 128;   // 32 m-tiles
  const int n0 = (j96 >> 2) * 128;              // 24 n-tiles

  f32x4 acc[4][4] = {};

  for (int k0 = 0; k0 < K; k0 += BK) {
    __syncthreads();
    #pragma unroll
    for (int i = 0; i < 2; ++i) {
      int c = wave * 64 + lane + 256 * i;       // chunk id (512 x 16B per tile)
      gload16(&A [(size_t)(m0 + (c >> 2)) * K + k0 + (c & 3) * 8],
              (char*)As + (size_t)(wave * 64 + 256 * i) * 16);
      gload16(&Bt[(size_t)(n0 + (c >> 2)) * K + k0 + (c & 3) * 8],
              (char*)Bs + (size_t)(wave * 64 + 256 * i) * 16);
    }
    __syncthreads();
    bf16x8 af[4], bfr[4];
    #pragma unroll
    for (int i = 0; i < 4; ++i)
      af[i]  = *(const bf16x8*)&As[(wm * 64 + i * 16 + r16) * BK + g * 8];
    #pragma unroll
    for (int j = 0; j < 4; ++j)
      bfr[j] = *(const bf16x8*)&Bs[(wn * 64 + j * 16 + r16) * BK + g * 8];
    #pragma unroll
    for (int i = 0; i < 4; ++i)
      #pragma unroll
      for (int j = 0; j < 4; ++j)
        acc[i][j] = __builtin_amdgcn_mfma_f32_16x16x32_bf16(af[i], bfr[j],
                                                            acc[i][j], 0, 0, 0);
  }

  #pragma unroll
  for (int i = 0; i < 4; ++i) {
    #pragma unroll
    for (int j = 0; j < 4; ++j) {
      #pragma unroll
      for (int r = 0; r < 4; ++r) {
        int m = m0 + wm * 64 + i * 16 + 4 * g + r;   // C row = (lane>>4)*4+reg
        int n = n0 + wn * 64 + j * 16 + r16;         // C col = lane&15
        float v = acc[i][j][r];
        int proj = n >> 10, w = n & 1023, h = w >> 6, d = w & 63;
        const float* bp = (proj == 0) ? b0 : (proj == 1) ? b1 : b2;
        v += bp[w];
        int b = m >> 11, s = m & 2047, bh = b * HEADSX + h;
        if (proj == 0)      qb [((size_t)bh * SSX + s) * HDX + d] =
                                (__bf16)(v * QSCALE);
        else if (proj == 1) kb [((size_t)bh * SSX + s) * HDX + d] = (__bf16)v;
        else                vtb[((size_t)bh * HDX + d) * SSX + s] = (__bf16)v;
      }
    }
  }
}

// ---------------- kernel 5: output GEMM, 128x64 tile ----------------
// 512 blocks = 2/CU; per wave 8 MFMA vs 6 b128-reads per K-step.
__global__ __launch_bounds__(256) void k_gemm_out(
    const __bf16* __restrict__ A,    // ctx [4096][1024]
    const __bf16* __restrict__ Bt,   // WoT [1024][1024]
    const float* __restrict__ bias, float* __restrict__ outf) {
  constexpr int BK = 32, K = 1024;
  __shared__ __bf16 As[128 * BK];    // 8 KB
  __shared__ __bf16 Bs[64 * BK];     // 4 KB
  const int tid = threadIdx.x, lane = tid & 63, wave = tid >> 6;
  const int g = lane >> 4, r16 = lane & 15;
  const int wm = wave & 1, wn = wave >> 1;
  const int id = blockIdx.x;                 // 512 blocks = 8 XCD x 64
  const int xcd = id & 7, j64 = id >> 3;
  const int m0 = (xcd * 4 + (j64 & 3)) * 128;   // 32 m-tiles
  const int n0 = (j64 >> 2) * 64;               // 16 n-tiles

  f32x4 acc[4][2] = {};

  for (int k0 = 0; k0 < K; k0 += BK) {
    __syncthreads();
    #pragma unroll
    for (int i = 0; i < 2; ++i) {
      int c = wave * 64 + lane + 256 * i;      // A: 512 chunks
      gload16(&A [(size_t)(m0 + (c >> 2)) * K + k0 + (c & 3) * 8],
              (char*)As + (size_t)(wave * 64 + 256 * i) * 16);
    }
    {
      int c = tid;                             // B: 256 chunks
      gload16(&Bt[(size_t)(n0 + (c >> 2)) * K + k0 + (c & 3) * 8],
              (char*)Bs + (size_t)(wave * 64) * 16);
    }
    __syncthreads();
    bf16x8 af[4], bfr[2];
    #pragma unroll
    for (int i = 0; i < 4; ++i)
      af[i]  = *(const bf16x8*)&As[(wm * 64 + i * 16 + r16) * BK + g * 8];
    #pragma unroll
    for (int j = 0; j < 2; ++j)
      bfr[j] = *(const bf16x8*)&Bs[(wn * 32 + j * 16 + r16) * BK + g * 8];
    #pragma unroll
    for (int i = 0; i < 4; ++i)
      #pragma unroll
      for (int j = 0; j < 2; ++j)
        acc[i][j] = __builtin_amdgcn_mfma_f32_16x16x32_bf16(af[i], bfr[j],
                                                            acc[i][j], 0, 0, 0);
  }

  #pragma unroll
  for (int i = 0; i < 4; ++i)
    #pragma unroll
    for (int j = 0; j < 2; ++j)
      #pragma unroll
      for (int r = 0; r < 4; ++r) {
        int m = m0 + wm * 64 + i * 16 + 4 * g + r;
        int n = n0 + wn * 32 + j * 16 + r16;
        outf[(size_t)m * DIMX + n] = acc[i][j][r] + bias[n];
      }
}

// -------- kernel 4: causal flash attention, paired q-tiles, FUSED --------
// Block p: q-tiles qL=p (ntL kv-tiles), qH=31-p (ntH) -> uniform 33 tiles.
// Fused subtile: each kf/vf LDS fragment is read ONCE and feeds both q-sets'
// MFMAs; the two softmax chains are independent (in-register dual pipeline).
__global__ __launch_bounds__(256, 2) void k_attn(
    const __bf16* __restrict__ qb, const __bf16* __restrict__ kb,
    const __bf16* __restrict__ vtb, __bf16* __restrict__ ctxb) {
  const int tid = threadIdx.x;
  const int lane = tid & 63, wq = tid >> 6;
  const int g = lane >> 4, r16 = lane & 15;

  // XCD-chunked mapping: id%8 = XCD; 4 consecutive bh per XCD.
  const int id = blockIdx.x;
  const int xcd = id & 7, idx = id >> 3;
  const int bh = xcd * 4 + (idx & 3);
  const int p  = idx >> 2;                 // pair index 0..15
  const int b = bh >> 4, h = bh & 15;

  const int ntL = p + 1, ntH = 32 - p;     // ntL <= 16 < ntH always
  const int q0L = p * 64 + wq * 16;
  const int q0H = (31 - p) * 64 + wq * 16;

  const __bf16* Q  = qb  + (size_t)bh * SSX * HDX;
  const __bf16* Kp = kb  + (size_t)bh * SSX * HDX;
  const __bf16* Vt = vtb + (size_t)bh * HDX * SSX;

  __shared__ __bf16 Ks[2][64 * 64];    // 2 x 8 KB
  __shared__ __bf16 Vs[2][64 * 64];    // 2 x 8 KB
  __shared__ unsigned Pld[8][512];     // [wave*2 + {H,L}] P^T scratch, 16 KB

  bf16x8 qfL[2], qfH[2];
  qfL[0] = *(const bf16x8*)&Q[(size_t)(q0L + r16) * HDX + g * 8];
  qfL[1] = *(const bf16x8*)&Q[(size_t)(q0L + r16) * HDX + 32 + g * 8];
  qfH[0] = *(const bf16x8*)&Q[(size_t)(q0H + r16) * HDX + g * 8];
  qfH[1] = *(const bf16x8*)&Q[(size_t)(q0H + r16) * HDX + 32 + g * 8];

  f32x4 accL[4] = {}, accH[4] = {};    // ctx^T: acc[j2][r]=ctx[d=j2*16+4g+r][q=r16]
  float mrunL = NEGF, lrunL = 0.f;
  float mrunH = NEGF, lrunH = 0.f;

  // stage tile t (64 kv x 64) of K and V. LDS chunk (r,cb) <- global (r, cb^(r&7))
  auto STAGE = [&](int buf, int t) {
    const int kv0 = t * 64;
    #pragma unroll
    for (int i = 0; i < 2; ++i) {
      int c = tid + 256 * i;
      int r = c >> 3;
      int cb = (c & 7) ^ (r & 7);
      gload16(&Kp[(size_t)(kv0 + r) * HDX + cb * 8],
              (char*)Ks[buf] + (size_t)(wq * 64 + 256 * i) * 16);
      gload16(&Vt[(size_t)r * SSX + kv0 + cb * 8],
              (char*)Vs[buf] + (size_t)(wq * 64 + 256 * i) * 16);
    }
  };

  // softmax + P pack/store for one q-set (q lane-local: scalar m/l)
  auto SM = [&](f32x4* sac, f32x4* acc, float& mrun, float& lrun,
                int qrow, bool last, int kv0, unsigned* pld) {
    float pv[4][4];
    float mt = NEGF;
    #pragma unroll
    for (int jj = 0; jj < 4; ++jj)
      #pragma unroll
      for (int r = 0; r < 4; ++r) {
        float s = sac[jj][r];
        if (last) {
          int kcol = kv0 + jj * 16 + 4 * g + r;
          s = (kcol > qrow) ? NEGF : s;
        }
        pv[jj][r] = s;
        mt = fmaxf(mt, s);
      }
    mt = fmaxf(mt, __shfl_xor(mt, 16));
    mt = fmaxf(mt, __shfl_xor(mt, 32));
    if (__any(mt > mrun)) {          // T13 defer-max (exact: P<=1 when skipped)
      float mnew = fmaxf(mrun, mt);
      float fac = exp2f(mrun - mnew);
      mrun = mnew;
      lrun *= fac;
      #pragma unroll
      for (int j2 = 0; j2 < 4; ++j2)
        #pragma unroll
        for (int r = 0; r < 4; ++r)
          acc[j2][r] *= fac;
    }
    float rs = 0.f;
    #pragma unroll
    for (int jj = 0; jj < 4; ++jj)
      #pragma unroll
      for (int r = 0; r < 4; ++r) {
        float px = exp2f(pv[jj][r] - mrun);
        pv[jj][r] = px;
        rs += px;
      }
    lrun += rs;                      // lane-partial; cross-g reduced at end
    #pragma unroll
    for (int jj = 0; jj < 4; ++jj)
      #pragma unroll
      for (int rp = 0; rp < 2; ++rp) {
        unsigned w;
        asm("v_cvt_pk_bf16_f32 %0, %1, %2"
            : "=v"(w) : "v"(pv[jj][2 * rp]), "v"(pv[jj][2 * rp + 1]));
        int c = jj * 8 + g * 2 + rp;                       // k/2
        int addr = r16 * 32 + (((c >> 2) ^ (r16 & 7)) << 2) + (c & 3);
        pld[addr] = w;
      }
  };

  // one staged kv-tile: QK (shared kf) -> SM(H[,L]) -> PV (shared vf)
  auto STEP = [&](auto dolc, int t, bool lastH) {
    constexpr bool doL = decltype(dolc)::value;
    const int cur = t & 1;
    if (t + 1 < ntH) STAGE(cur ^ 1, t + 1);   // async prefetch next tile
    const int kv0 = t * 64;

    f32x4 sacH[4] = {}, sacL[4] = {};
    __builtin_amdgcn_s_setprio(1);
    #pragma unroll
    for (int kk = 0; kk < 2; ++kk)
      #pragma unroll
      for (int jj = 0; jj < 4; ++jj) {
        int rr = jj * 16 + r16;
        bf16x8 kf = *(const bf16x8*)
            &Ks[cur][rr * 64 + (((kk << 2) + g) ^ (rr & 7)) * 8];
        sacH[jj] = __builtin_amdgcn_mfma_f32_16x16x32_bf16(kf, qfH[kk],
                                                           sacH[jj], 0, 0, 0);
        if constexpr (doL)
          sacL[jj] = __builtin_amdgcn_mfma_f32_16x16x32_bf16(kf, qfL[kk],
                                                             sacL[jj], 0, 0, 0);
      }
    __builtin_amdgcn_s_setprio(0);

    SM(sacH, accH, mrunH, lrunH, q0H + r16, lastH, kv0, &Pld[wq * 2][0]);
    if constexpr (doL)
      SM(sacL, accL, mrunL, lrunL, q0L + r16, t == ntL - 1, kv0,
         &Pld[wq * 2 + 1][0]);

    bf16x8 pfH[2], pfL[2];
    #pragma unroll
    for (int half = 0; half < 2; ++half) {
      int c = half * 16 + g * 4;
      int addr = r16 * 32 + (((c >> 2) ^ (r16 & 7)) << 2);
      pfH[half] = *(const bf16x8*)&Pld[wq * 2][addr];
      if constexpr (doL) pfL[half] = *(const bf16x8*)&Pld[wq * 2 + 1][addr];
    }
    __builtin_amdgcn_s_setprio(1);
    #pragma unroll
    for (int j2 = 0; j2 < 4; ++j2)
      #pragma unroll
      for (int half = 0; half < 2; ++half) {
        int dd = j2 * 16 + r16;
        bf16x8 vf = *(const bf16x8*)
            &Vs[cur][dd * 64 + (((half << 2) + g) ^ (dd & 7)) * 8];
        accH[j2] = __builtin_amdgcn_mfma_f32_16x16x32_bf16(vf, pfH[half],
                                                           accH[j2], 0, 0, 0);
        if constexpr (doL)
          accL[j2] = __builtin_amdgcn_mfma_f32_16x16x32_bf16(vf, pfL[half],
                                                             accL[j2], 0, 0, 0);
      }
    __builtin_amdgcn_s_setprio(0);
  };

  STAGE(0, 0);
  __syncthreads();

  int t = 0;
  for (; t < ntL; ++t) {             // both q-sets active (ntL < ntH always)
    STEP(BoolC<true>{}, t, false);
    __syncthreads();
  }
  for (; t < ntH; ++t) {             // qH only
    STEP(BoolC<false>{}, t, t == ntH - 1);
    __syncthreads();
  }

  auto EPIL = [&](f32x4* acc, float lrun, int q0) {
    lrun += __shfl_xor(lrun, 16);
    lrun += __shfl_xor(lrun, 32);
    const float inv = 1.f / lrun;
    const int s = q0 + r16;
    #pragma unroll
    for (int j2 = 0; j2 < 4; ++j2)
      #pragma unroll
      for (int r = 0; r < 4; ++r) {
        int d = j2 * 16 + 4 * g + r;
        ctxb[((size_t)(b * SSX + s)) * DIMX + h * HDX + d] =
            (__bf16)(acc[j2][r] * inv);
      }
  };
  EPIL(accH, lrunH, q0H);
  EPIL(accL, lrunL, q0L);
}

extern "C" void kernel_launch(void* const* d_in, const int* in_sizes, int n_in,
                              void* d_out, int out_size, void* d_ws,
                              size_t ws_size, hipStream_t stream) {
  const float* x  = (const float*)d_in[0];
  const float* Wq = (const float*)d_in[1];
  const float* bq = (const float*)d_in[2];
  const float* Wk = (const float*)d_in[3];
  const float* bk = (const float*)d_in[4];
  const float* Wv = (const float*)d_in[5];
  const float* bv = (const float*)d_in[6];
  const float* Wo = (const float*)d_in[7];
  const float* bo = (const float*)d_in[8];
  float* out = (float*)d_out;

  char* ws = (char*)d_ws;                       // needs 40 MB
  __bf16* xb    = (__bf16*)(ws);                // 8 MB, reused as ctxb later
  __bf16* wqkvT = (__bf16*)(ws + ((size_t)8  << 20));  // 6 MB
  __bf16* woT   = (__bf16*)(ws + ((size_t)14 << 20));  // 2 MB
  __bf16* qb    = (__bf16*)(ws + ((size_t)16 << 20));  // 8 MB
  __bf16* kb    = (__bf16*)(ws + ((size_t)24 << 20));  // 8 MB
  __bf16* vtb   = (__bf16*)(ws + ((size_t)32 << 20));  // 8 MB (V^T)
  __bf16* ctxb  = xb;   // x dead after QKV GEMM

  k_prep<<<5120, 256, 0, stream>>>(x, Wq, Wk, Wv, Wo, xb, wqkvT, woT);
  k_gemm_qkv<<<768, 256, 0, stream>>>(xb, wqkvT, bq, bk, bv, qb, kb, vtb);
  k_attn<<<512, 256, 0, stream>>>(qb, kb, vtb, ctxb);
  k_gemm_out<<<512, 256, 0, stream>>>(ctxb, woT, bo, out);
}